// Round 7
// baseline (100.850 us; speedup 1.0000x reference)
//
#include <hip/hip_runtime.h>
#include <hip/hip_bf16.h>
#include <math.h>

// QNN: 8 qubits, DIM=256, 2 entangling layers, B samples.
//  - RX(x_q) fuses with layer-1 RX -> product state v_q (V0,V1).
//  - CNOT ring 1 folded into product expansion; R7: expansion refactored as
//      S[row][col] = RF[row] * TH[(h1, h1^h0)][col0] * TC[col][r0]
//    (rank-8 split: only V0,V1,V4 cross row/col), tables built once/sample
//    in a parallel phase -> per-sample front-end = 3 LDS reads + 6 cmuls.
//  - Layer-2 gates sample-independent: phi = A*S*B^T via 4x mfma 16x16x32 bf16.
//  - CNOT ring 2 + <Z_w> + cross-lane reduction folded into a constant sign
//    matrix applied as mfma_f32_16x16x32_f16 chain (R6).
// Mapping: 1 wave = 16 samples; per sample lane L holds S col n=L&15,
// rows 4h..4h+3 (h=L>>4).

typedef float f2 __attribute__((ext_vector_type(2)));
typedef float f4 __attribute__((ext_vector_type(4)));
typedef short short8 __attribute__((ext_vector_type(8)));
typedef _Float16 half8 __attribute__((ext_vector_type(8)));
typedef _Float16 h2v  __attribute__((ext_vector_type(2)));

// complex mul, 2 VOP3P ops (verified R3-R6)
__device__ __forceinline__ f2 cmul_pk(f2 a, f2 b) {
    f2 t, d;
    asm("v_pk_mul_f32 %0, %1, %2 op_sel:[0,0] op_sel_hi:[0,1]"
        : "=v"(t) : "v"(a), "v"(b));                       // (ax*bx, ax*by)
    asm("v_pk_fma_f32 %0, %1, %2, %3 op_sel:[1,1,0] op_sel_hi:[1,0,1] neg_lo:[1,0,0] neg_hi:[0,0,0]"
        : "=v"(d) : "v"(a), "v"(b), "v"(t));               // (-ay*by+t.x, ay*bx+t.y)
    return d;
}

__device__ __forceinline__ f2 h2f(unsigned u) {
    h2v h; __builtin_memcpy(&h, &u, 4);
    return (f2){(float)h.x, (float)h.y};
}

// ---------------- setup (identical to R6) ----------------
__global__ void qnn_setup(const float* __restrict__ w, float* __restrict__ p) {
    int t = threadIdx.x;
    if (t < 8) {
        int q = t;
        float cb = cosf(w[q*3+1]*0.5f), sb = sinf(w[q*3+1]*0.5f);
        float cg = cosf(w[q*3+2]*0.5f), sg = sinf(w[q*3+2]*0.5f);
        p[q] = w[q*3+0];
        float* K = p + 8 + q*8;
        K[0] = cg*cb;  K[1] = -sg*cb;      // K1
        K[2] = sg*sb;  K[3] = cg*sb;       // K2
        K[4] = cg*sb;  K[5] = sg*sb;       // K3
        K[6] = sg*cb;  K[7] = -cg*cb;      // K4
    }
    float G[8][2][2][2];
    for (int q = 0; q < 8; ++q) {
        const float* wq = w + (8+q)*3;
        float ca = cosf(wq[0]*0.5f), sa = sinf(wq[0]*0.5f);
        float cb = cosf(wq[1]*0.5f), sb = sinf(wq[1]*0.5f);
        float cg = cosf(wq[2]*0.5f), sg = sinf(wq[2]*0.5f);
        float A = cb*ca, Bv = sb*sa, C = sb*ca, D = cb*sa;
        float g00r = cg*A + sg*Bv, g00i = cg*Bv - sg*A;
        float g01r = -(cg*C + sg*D), g01i = sg*C - cg*D;
        G[q][0][0][0]=g00r;  G[q][0][0][1]=g00i;
        G[q][0][1][0]=g01r;  G[q][0][1][1]=g01i;
        G[q][1][0][0]=-g01r; G[q][1][0][1]=g01i;
        G[q][1][1][0]=g00r;  G[q][1][1][1]=-g00i;
    }
    int m = t & 15, k2 = t >> 4;
    float ar = 1.f, ai = 0.f, br = 1.f, bi = 0.f;
    for (int j = 0; j < 4; ++j) {
        int bm = (m >> (3-j)) & 1, bk = (k2 >> (3-j)) & 1;
        float gr = G[j][bm][bk][0],  gi = G[j][bm][bk][1];
        float nr = ar*gr - ai*gi, ni = ar*gi + ai*gr; ar = nr; ai = ni;
        float hr = G[4+j][bm][bk][0], hi = G[4+j][bm][bk][1];
        float mr = br*hr - bi*hi, mi = br*hi + bi*hr; br = mr; bi = mi;
    }
    __hip_bfloat16* A1 = (__hip_bfloat16*)((char*)p + 512);
    __hip_bfloat16* A2 = A1 + 512;
    __hip_bfloat16* B1 = A1 + 1024;
    __hip_bfloat16* B2 = A1 + 1536;
    int p0 = ((k2 >> 3)*16 + m)*8 + (k2 & 7);
    int k3 = k2 + 16;
    int p1 = ((k3 >> 3)*16 + m)*8 + (k3 & 7);
    A1[p0] = __float2bfloat16(ar);   A1[p1] = __float2bfloat16(-ai);
    A2[p0] = __float2bfloat16(ai);   A2[p1] = __float2bfloat16(ar);
    B1[p0] = __float2bfloat16(br);   B1[p1] = __float2bfloat16(-bi);
    B2[p0] = __float2bfloat16(bi);   B2[p1] = __float2bfloat16(br);

    // sign table for the reduction GEMM (R6, verified)
    const int cls[8] = {2, 0, 1, 2, 2, 2, 2, 2};
    const int msk[8] = {31, 48, 48, 48, 56, 60, 62, 63};
    _Float16* SG = (_Float16*)((char*)p + 4608);
    for (int e = t; e < 512; e += 256) {
        int tt = e >> 6, l = e & 63, n = l & 15, quad = l >> 4;
        for (int j = 0; j < 8; ++j) {
            int k  = tt*32 + quad*8 + j;
            int Lp = k >> 2, c = k & 3;
            float v = 0.f;
            if (n < 8 && c == cls[n])
                v = (__popc(msk[n] & Lp) & 1) ? -1.f : 1.f;
            SG[e*8 + j] = (_Float16)v;
        }
    }
}

// per-wave LDS: S 1024 | M 1280 | TH 1280 | TC 4352 | RF 1280 | R 4352 = 13568
// (VT from phase A is aliased into the R region - dead before R is written)
#define WAVE_LDS 13568

__global__ __launch_bounds__(256) void qnn_main(
        const float* __restrict__ x, const float* __restrict__ p,
        float* __restrict__ out, int B)
{
    __shared__ __align__(16) char smem[4 * WAVE_LDS];
    const int lane = threadIdx.x & 63;
    const int wid  = threadIdx.x >> 6;
    const int L = lane;
    const int b0 = (blockIdx.x * 4 + wid) * 16;
    if (b0 >= B) return;

    char* wb  = smem + wid * WAVE_LDS;
    char* Sb  = wb;
    char* Mb  = wb + 1024;
    char* THb = wb + 2304;
    char* TCb = wb + 3584;
    char* RFb = wb + 7936;
    char* Rb  = wb + 9216;              // R staging; VT aliased here first
    f4*   VT  = (f4*)Rb;

    // constant frags (loop-invariant)
    const short8* fr = (const short8*)((const char*)p + 512);
    short8 A1f = fr[L], A2f = fr[64 + L], B1f = fr[128 + L], B2f = fr[192 + L];
    const half8* sgt = (const half8*)((const char*)p + 4608);

    // ---- phase A: build V for 16 samples x 8 qubits (2 builds/lane) ----
    {
        int sI = L >> 2, qp = (L & 3) * 2;
        float2 xv  = ((const float2*)x)[(size_t)(b0 + sI)*4 + (L & 3)];
        float2 w0p = ((const float2*)p)[qp >> 1];
        const f4* Kt = (const f4*)(p + 8);
#pragma unroll
        for (int u = 0; u < 2; ++u) {
            int q = qp + u;
            float ang = (u ? xv.y : xv.x) + (u ? w0p.y : w0p.x);
            float rev = ang * 0.07957747154594767f;      // (ang/2)/(2pi)
            float ca = __builtin_amdgcn_cosf(rev);
            float sa = __builtin_amdgcn_sinf(rev);
            f4 Ka = Kt[q*2], Kb = Kt[q*2+1];
            f4 v;
            v.x = ca*Ka.x + sa*Ka.z;  v.y = ca*Ka.y + sa*Ka.w;   // V0
            v.z = ca*Kb.x + sa*Kb.z;  v.w = ca*Kb.y + sa*Kb.w;   // V1
            VT[sI*8 + q] = v;
        }
    }
    // same-wave LDS is in-order; all regions per-wave -> no barriers

    // ---- phase B: build TH/TC/RF tables (4 lanes per sample) ----
    {
        int sI = L >> 2, j = L & 3;
        const f4* Vs = VT + sI*8;
        f4 q0v = Vs[0], q1v = Vs[1], q2v = Vs[2], q3v = Vs[3];
        f4 q4v = Vs[4], q5v = Vs[5], q6v = Vs[6], q7v = Vs[7];
        f2 V0a = {q0v.x,q0v.y}, V0b = {q0v.z,q0v.w};
        f2 V1a = {q1v.x,q1v.y}, V1b = {q1v.z,q1v.w};
        f2 V2a = {q2v.x,q2v.y}, V2b = {q2v.z,q2v.w};
        f2 V3a = {q3v.x,q3v.y}, V3b = {q3v.z,q3v.w};
        f2 V4a = {q4v.x,q4v.y}, V4b = {q4v.z,q4v.w};
        f2 V5a = {q5v.x,q5v.y}, V5b = {q5v.z,q5v.w};
        f2 V6a = {q6v.x,q6v.y}, V6b = {q6v.z,q6v.w};
        f2 V7a = {q7v.x,q7v.y}, V7b = {q7v.z,q7v.w};
        // TH slot j = (t1,t2) = (j>>1, j&1); entries col0 = 0,1
        int t1 = j >> 1, t2 = j & 1;
        f2 th0 = cmul_pk(t1 ? V0b : V0a, t2 ? V1b : V1a);
        f2 th1 = cmul_pk(t1 ? V0a : V0b, t2 ? V1a : V1b);
        *(f4*)(THb + sI*80 + j*16) = (f4){th0.x, th0.y, th1.x, th1.y};
        // TC cols 4j..4j+3: col3 = j>>1, col2 = j&1
        int col3 = j >> 1, col2 = j & 1;
        f2 v5s  = (col3 ^ col2) ? V5b : V5a;
        f2 p6_0 = cmul_pk(v5s, col2 ? V6b : V6a);     // col1 = 0
        f2 p6_1 = cmul_pk(v5s, col2 ? V6a : V6b);     // col1 = 1
        f2 V4lo = col3 ? V4b : V4a;                   // V4[col3]     (t3=0)
        f2 V4hi = col3 ? V4a : V4b;                   // V4[1^col3]   (t3=1)
#pragma unroll
        for (int c = 0; c < 4; ++c) {
            int c1 = c >> 1, c0 = c & 1;
            f2 cf = cmul_pk(c1 ? p6_1 : p6_0, (c1 ^ c0) ? V7b : V7a);
            f2 e0 = cmul_pk(cf, V4lo);
            f2 e1 = cmul_pk(cf, V4hi);
            *(f4*)(TCb + sI*272 + (4*j + c)*16) = (f4){e0.x, e0.y, e1.x, e1.y};
        }
        // RF rows 4j..4j+3 (f16): RF[row] = V2[row2^row1]*V3[row1^row0]
        unsigned rr[4];
#pragma unroll
        for (int r = 0; r < 4; ++r) {
            int r1 = r >> 1, r0 = r & 1;
            f2 rf = cmul_pk(((j & 1) ^ r1) ? V2b : V2a, (r1 ^ r0) ? V3b : V3a);
            auto pk = __builtin_amdgcn_cvt_pkrtz(rf.x, rf.y);
            __builtin_memcpy(&rr[r], &pk, 4);
        }
        *(uint4*)(RFb + sI*80 + j*16) = (uint4){rr[0], rr[1], rr[2], rr[3]};
    }

    // ---- hoisted lane constants ----
    const int hq  = L >> 4;
    const int col = L & 15;
    const int th_t1 = hq >> 1, th_t2 = (hq >> 1) ^ (hq & 1);
    char* THl = THb + ((th_t1*2 + th_t2)*2 + (col & 1))*8;
    char* TCl = TCb + col*16;
    char* RFl = RFb + hq*16;

    char* wSr = Sb + col*32 + hq*8;     char* wSi = wSr + 512;
    char* rS  = Sb + col*32 + (hq & 1)*16 + (hq >> 1)*512;
    char* wM  = Mb + hq*320 + col*4;
    char* rM  = Mb + col*80 + (hq & 1)*32;
    char* Rw  = Rb + L*8;
    char* Rr  = Rb + (col & 7)*544 + hq*16;
    const unsigned selM = (hq >> 1) ? 0x07060302u : 0x05040100u;
    const f4 zz = {0.f, 0.f, 0.f, 0.f};

    for (int h = 0; h < 2; ++h) {
        for (int s8 = 0; s8 < 8; ++s8) {
            const int s = h*8 + s8;
            // ---- front-end: a_r = RF[4hq+r] * TH * TC[col][r&1] ----
            f2 u  = *(f2*)(THl + s*80);
            f4 tc = *(f4*)(TCl + s*272);
            uint4 rf = *(uint4*)(RFl + s*80);
            f2 g0 = cmul_pk(u, (f2){tc.x, tc.y});
            f2 g1 = cmul_pk(u, (f2){tc.z, tc.w});
            f2 a0 = cmul_pk(h2f(rf.x), g0);
            f2 a1 = cmul_pk(h2f(rf.y), g1);
            f2 a2 = cmul_pk(h2f(rf.z), g0);
            f2 a3 = cmul_pk(h2f(rf.w), g1);
            // ---- glue1: S -> LDS bf16, read B-frag ----
            unsigned r0 = __float_as_uint(a0.x)+0x8000u, r1 = __float_as_uint(a1.x)+0x8000u;
            unsigned r2 = __float_as_uint(a2.x)+0x8000u, r3 = __float_as_uint(a3.x)+0x8000u;
            unsigned i0 = __float_as_uint(a0.y)+0x8000u, i1 = __float_as_uint(a1.y)+0x8000u;
            unsigned i2 = __float_as_uint(a2.y)+0x8000u, i3 = __float_as_uint(a3.y)+0x8000u;
            uint2 pr = { __builtin_amdgcn_perm(r1, r0, 0x07060302u),
                         __builtin_amdgcn_perm(r3, r2, 0x07060302u) };
            uint2 pi = { __builtin_amdgcn_perm(i1, i0, 0x07060302u),
                         __builtin_amdgcn_perm(i3, i2, 0x07060302u) };
            *(uint2*)wSr = pr;
            *(uint2*)wSi = pi;
            short8 sfrag = *(short8*)rS;
            // ---- stage-1 MFMA: M = A * S ----
            f4 mr = __builtin_amdgcn_mfma_f32_16x16x32_bf16(A1f, sfrag, zz, 0, 0, 0);
            f4 mi = __builtin_amdgcn_mfma_f32_16x16x32_bf16(A2f, sfrag, zz, 0, 0, 0);
            // ---- glue2: M -> LDS (stride 80B), read A-frag ----
            unsigned m0 = __builtin_amdgcn_perm(__float_as_uint(mi[0])+0x8000u,
                                                __float_as_uint(mr[0])+0x8000u, 0x07060302u);
            unsigned m1 = __builtin_amdgcn_perm(__float_as_uint(mi[1])+0x8000u,
                                                __float_as_uint(mr[1])+0x8000u, 0x07060302u);
            unsigned m2 = __builtin_amdgcn_perm(__float_as_uint(mi[2])+0x8000u,
                                                __float_as_uint(mr[2])+0x8000u, 0x07060302u);
            unsigned m3 = __builtin_amdgcn_perm(__float_as_uint(mi[3])+0x8000u,
                                                __float_as_uint(mr[3])+0x8000u, 0x07060302u);
            *(unsigned*)(wM +   0) = m0;  *(unsigned*)(wM +  80) = m1;
            *(unsigned*)(wM + 160) = m2;  *(unsigned*)(wM + 240) = m3;
            uint4 da = *(uint4*)rM;
            uint4 db = *(uint4*)(rM + 16);
            uint4 nf;
            nf.x = __builtin_amdgcn_perm(da.y, da.x, selM);
            nf.y = __builtin_amdgcn_perm(da.w, da.z, selM);
            nf.z = __builtin_amdgcn_perm(db.y, db.x, selM);
            nf.w = __builtin_amdgcn_perm(db.w, db.z, selM);
            short8 nfrag;
            __builtin_memcpy(&nfrag, &nf, 16);
            // ---- stage-2 MFMA: phi = M * B^T ----
            f4 pr4 = __builtin_amdgcn_mfma_f32_16x16x32_bf16(nfrag, B1f, zz, 0, 0, 0);
            f4 pi4 = __builtin_amdgcn_mfma_f32_16x16x32_bf16(nfrag, B2f, zz, 0, 0, 0);
            // ---- probs + in-lane 4-WHT -> 3 classes -> R staging ----
            float Q0 = pr4[0]*pr4[0] + pi4[0]*pi4[0];
            float Q1 = pr4[1]*pr4[1] + pi4[1]*pi4[1];
            float Q2 = pr4[2]*pr4[2] + pi4[2]*pi4[2];
            float Q3 = pr4[3]*pr4[3] + pi4[3]*pi4[3];
            float s01 = Q0 + Q1, s23 = Q2 + Q3;
            float S00 = s01 + s23;
            float S10 = s01 - s23;
            float S11 = (Q0 - Q1) - (Q2 - Q3);
            auto h01 = __builtin_amdgcn_cvt_pkrtz(S00, S10);
            auto h23 = __builtin_amdgcn_cvt_pkrtz(S11, 0.f);
            uint2 wv;
            __builtin_memcpy(&wv.x, &h01, 4);
            __builtin_memcpy(&wv.y, &h23, 4);
            *(uint2*)(Rw + s8*544) = wv;
        }
        // ---- epilogue: out[s][w] = R x Sgn (8 chained f16 MFMAs) ----
        f4 acc = zz;
#pragma unroll
        for (int tt = 0; tt < 8; ++tt) {
            uint4 rv = *(uint4*)(Rr + tt*64);
            half8 af;
            __builtin_memcpy(&af, &rv, 16);
            acc = __builtin_amdgcn_mfma_f32_16x16x32_f16(af, sgt[tt*64 + L], acc, 0, 0, 0);
        }
        if (hq < 2 && col < 8) {
            size_t base = (size_t)(b0 + h*8 + hq*4) * 8 + col;
            out[base     ] = acc[0];
            out[base +  8] = acc[1];
            out[base + 16] = acc[2];
            out[base + 24] = acc[3];
        }
    }
}

extern "C" void kernel_launch(void* const* d_in, const int* in_sizes, int n_in,
                              void* d_out, int out_size, void* d_ws, size_t ws_size,
                              hipStream_t stream) {
    const float* x = (const float*)d_in[0];
    const float* w = (const float*)d_in[1];
    float* outp    = (float*)d_out;
    float* params  = (float*)d_ws;        // ~12.8 KB used
    int B = in_sizes[0] / 8;

    qnn_setup<<<1, 256, 0, stream>>>(w, params);
    int blocks = (B + 63) / 64;           // 4 waves/block, 16 samples/wave
    qnn_main<<<blocks, 256, 0, stream>>>(x, params, outp, B);
}

// Round 8
// 92.482 us; speedup vs baseline: 1.0905x; 1.0905x over previous
//
#include <hip/hip_runtime.h>
#include <hip/hip_bf16.h>
#include <math.h>

// QNN: 8 qubits, DIM=256, 2 entangling layers, B samples.
//  - RX(x_q) fuses with layer-1 RX -> product state v_q (V0,V1).
//  - CNOT ring 1 folded into product expansion; rank-8 split (R7):
//      S[row][col] = RF[row] * TH[(h1,h1^h0)][col0] * TC[col][r0]
//  - Layer-2 gates sample-independent: phi = A*S*B^T via 4x mfma 16x16x32 bf16.
//  - CNOT ring 2 + <Z_w> + cross-lane reduction folded into a constant sign
//    matrix applied as mfma_f32_16x16x32_f16 chain (R6).
// R8: LDS diet -> 10240 B/wave (40960/block, exactly 4 blocks/CU):
//     TH & TC tables stored f16, RF stride 80->64, R stride 544->528.
//     R7's 54272 B/block rounded to 54784 -> 2 blocks/CU -> 17% occupancy,
//     latency-bound (5 serial LDS round-trips/iter). Restore TLP.

typedef float f2 __attribute__((ext_vector_type(2)));
typedef float f4 __attribute__((ext_vector_type(4)));
typedef short short8 __attribute__((ext_vector_type(8)));
typedef _Float16 half8 __attribute__((ext_vector_type(8)));
typedef _Float16 h2v  __attribute__((ext_vector_type(2)));

// complex mul, 2 VOP3P ops (verified R3-R7)
__device__ __forceinline__ f2 cmul_pk(f2 a, f2 b) {
    f2 t, d;
    asm("v_pk_mul_f32 %0, %1, %2 op_sel:[0,0] op_sel_hi:[0,1]"
        : "=v"(t) : "v"(a), "v"(b));                       // (ax*bx, ax*by)
    asm("v_pk_fma_f32 %0, %1, %2, %3 op_sel:[1,1,0] op_sel_hi:[1,0,1] neg_lo:[1,0,0] neg_hi:[0,0,0]"
        : "=v"(d) : "v"(a), "v"(b), "v"(t));               // (-ay*by+t.x, ay*bx+t.y)
    return d;
}

__device__ __forceinline__ f2 h2f(unsigned u) {
    h2v h; __builtin_memcpy(&h, &u, 4);
    return (f2){(float)h.x, (float)h.y};
}
__device__ __forceinline__ unsigned pkh(f2 v) {
    auto pk = __builtin_amdgcn_cvt_pkrtz(v.x, v.y);
    unsigned u; __builtin_memcpy(&u, &pk, 4);
    return u;
}

// ---------------- setup (identical to R6/R7) ----------------
__global__ void qnn_setup(const float* __restrict__ w, float* __restrict__ p) {
    int t = threadIdx.x;
    if (t < 8) {
        int q = t;
        float cb = cosf(w[q*3+1]*0.5f), sb = sinf(w[q*3+1]*0.5f);
        float cg = cosf(w[q*3+2]*0.5f), sg = sinf(w[q*3+2]*0.5f);
        p[q] = w[q*3+0];
        float* K = p + 8 + q*8;
        K[0] = cg*cb;  K[1] = -sg*cb;      // K1
        K[2] = sg*sb;  K[3] = cg*sb;       // K2
        K[4] = cg*sb;  K[5] = sg*sb;       // K3
        K[6] = sg*cb;  K[7] = -cg*cb;      // K4
    }
    float G[8][2][2][2];
    for (int q = 0; q < 8; ++q) {
        const float* wq = w + (8+q)*3;
        float ca = cosf(wq[0]*0.5f), sa = sinf(wq[0]*0.5f);
        float cb = cosf(wq[1]*0.5f), sb = sinf(wq[1]*0.5f);
        float cg = cosf(wq[2]*0.5f), sg = sinf(wq[2]*0.5f);
        float A = cb*ca, Bv = sb*sa, C = sb*ca, D = cb*sa;
        float g00r = cg*A + sg*Bv, g00i = cg*Bv - sg*A;
        float g01r = -(cg*C + sg*D), g01i = sg*C - cg*D;
        G[q][0][0][0]=g00r;  G[q][0][0][1]=g00i;
        G[q][0][1][0]=g01r;  G[q][0][1][1]=g01i;
        G[q][1][0][0]=-g01r; G[q][1][0][1]=g01i;
        G[q][1][1][0]=g00r;  G[q][1][1][1]=-g00i;
    }
    int m = t & 15, k2 = t >> 4;
    float ar = 1.f, ai = 0.f, br = 1.f, bi = 0.f;
    for (int j = 0; j < 4; ++j) {
        int bm = (m >> (3-j)) & 1, bk = (k2 >> (3-j)) & 1;
        float gr = G[j][bm][bk][0],  gi = G[j][bm][bk][1];
        float nr = ar*gr - ai*gi, ni = ar*gi + ai*gr; ar = nr; ai = ni;
        float hr = G[4+j][bm][bk][0], hi = G[4+j][bm][bk][1];
        float mr = br*hr - bi*hi, mi = br*hi + bi*hr; br = mr; bi = mi;
    }
    __hip_bfloat16* A1 = (__hip_bfloat16*)((char*)p + 512);
    __hip_bfloat16* A2 = A1 + 512;
    __hip_bfloat16* B1 = A1 + 1024;
    __hip_bfloat16* B2 = A1 + 1536;
    int p0 = ((k2 >> 3)*16 + m)*8 + (k2 & 7);
    int k3 = k2 + 16;
    int p1 = ((k3 >> 3)*16 + m)*8 + (k3 & 7);
    A1[p0] = __float2bfloat16(ar);   A1[p1] = __float2bfloat16(-ai);
    A2[p0] = __float2bfloat16(ai);   A2[p1] = __float2bfloat16(ar);
    B1[p0] = __float2bfloat16(br);   B1[p1] = __float2bfloat16(-bi);
    B2[p0] = __float2bfloat16(bi);   B2[p1] = __float2bfloat16(br);

    // sign table for the reduction GEMM (R6, verified)
    const int cls[8] = {2, 0, 1, 2, 2, 2, 2, 2};
    const int msk[8] = {31, 48, 48, 48, 56, 60, 62, 63};
    _Float16* SG = (_Float16*)((char*)p + 4608);
    for (int e = t; e < 512; e += 256) {
        int tt = e >> 6, l = e & 63, n = l & 15, quad = l >> 4;
        for (int j = 0; j < 8; ++j) {
            int k  = tt*32 + quad*8 + j;
            int Lp = k >> 2, c = k & 3;
            float v = 0.f;
            if (n < 8 && c == cls[n])
                v = (__popc(msk[n] & Lp) & 1) ? -1.f : 1.f;
            SG[e*8 + j] = (_Float16)v;
        }
    }
}

// per-wave LDS layout (10240 B total):
//   S 1024 | M 1280 | TH 512 (f16) | TC 2176 (f16, stride 136) |
//   RF 1024 (stride 64) | R 4224 (stride 528)
// VT (phase A, 2048 B) aliased into R region - dead before R writes.
#define WAVE_LDS 10240

__global__ __launch_bounds__(256, 4) void qnn_main(
        const float* __restrict__ x, const float* __restrict__ p,
        float* __restrict__ out, int B)
{
    __shared__ __align__(16) char smem[4 * WAVE_LDS];
    const int lane = threadIdx.x & 63;
    const int wid  = threadIdx.x >> 6;
    const int L = lane;
    const int b0 = (blockIdx.x * 4 + wid) * 16;
    if (b0 >= B) return;

    char* wb  = smem + wid * WAVE_LDS;
    char* Sb  = wb;
    char* Mb  = wb + 1024;
    char* THb = wb + 2304;
    char* TCb = wb + 2816;
    char* RFb = wb + 4992;
    char* Rb  = wb + 6016;              // R staging; VT aliased here first
    f4*   VT  = (f4*)Rb;

    // constant frags (loop-invariant)
    const short8* fr = (const short8*)((const char*)p + 512);
    short8 A1f = fr[L], A2f = fr[64 + L], B1f = fr[128 + L], B2f = fr[192 + L];
    const half8* sgt = (const half8*)((const char*)p + 4608);

    // ---- phase A: build V for 16 samples x 8 qubits (2 builds/lane) ----
    {
        int sI = L >> 2, qp = (L & 3) * 2;
        float2 xv  = ((const float2*)x)[(size_t)(b0 + sI)*4 + (L & 3)];
        float2 w0p = ((const float2*)p)[qp >> 1];
        const f4* Kt = (const f4*)(p + 8);
#pragma unroll
        for (int u = 0; u < 2; ++u) {
            int q = qp + u;
            float ang = (u ? xv.y : xv.x) + (u ? w0p.y : w0p.x);
            float rev = ang * 0.07957747154594767f;      // (ang/2)/(2pi)
            float ca = __builtin_amdgcn_cosf(rev);
            float sa = __builtin_amdgcn_sinf(rev);
            f4 Ka = Kt[q*2], Kb = Kt[q*2+1];
            f4 v;
            v.x = ca*Ka.x + sa*Ka.z;  v.y = ca*Ka.y + sa*Ka.w;   // V0
            v.z = ca*Kb.x + sa*Kb.z;  v.w = ca*Kb.y + sa*Kb.w;   // V1
            VT[sI*8 + q] = v;
        }
    }
    // same-wave LDS is in-order; all regions per-wave -> no barriers

    // ---- phase B: build TH/TC/RF tables (4 lanes per sample) ----
    {
        int sI = L >> 2, j = L & 3;
        const f4* Vs = VT + sI*8;
        f4 q0v = Vs[0], q1v = Vs[1], q2v = Vs[2], q3v = Vs[3];
        f4 q4v = Vs[4], q5v = Vs[5], q6v = Vs[6], q7v = Vs[7];
        f2 V0a = {q0v.x,q0v.y}, V0b = {q0v.z,q0v.w};
        f2 V1a = {q1v.x,q1v.y}, V1b = {q1v.z,q1v.w};
        f2 V2a = {q2v.x,q2v.y}, V2b = {q2v.z,q2v.w};
        f2 V3a = {q3v.x,q3v.y}, V3b = {q3v.z,q3v.w};
        f2 V4a = {q4v.x,q4v.y}, V4b = {q4v.z,q4v.w};
        f2 V5a = {q5v.x,q5v.y}, V5b = {q5v.z,q5v.w};
        f2 V6a = {q6v.x,q6v.y}, V6b = {q6v.z,q6v.w};
        f2 V7a = {q7v.x,q7v.y}, V7b = {q7v.z,q7v.w};
        // TH slot j = (t1,t2) = (j>>1, j&1); entries col0 = 0,1  (f16)
        int t1 = j >> 1, t2 = j & 1;
        f2 th0 = cmul_pk(t1 ? V0b : V0a, t2 ? V1b : V1a);
        f2 th1 = cmul_pk(t1 ? V0a : V0b, t2 ? V1a : V1b);
        *(uint2*)(THb + sI*32 + j*8) = (uint2){pkh(th0), pkh(th1)};
        // TC cols 4j..4j+3 (f16): col3 = j>>1, col2 = j&1
        int col3 = j >> 1, col2 = j & 1;
        f2 v5s  = (col3 ^ col2) ? V5b : V5a;
        f2 p6_0 = cmul_pk(v5s, col2 ? V6b : V6a);     // col1 = 0
        f2 p6_1 = cmul_pk(v5s, col2 ? V6a : V6b);     // col1 = 1
        f2 V4lo = col3 ? V4b : V4a;                   // V4[col3]     (r0=0)
        f2 V4hi = col3 ? V4a : V4b;                   // V4[1^col3]   (r0=1)
#pragma unroll
        for (int c = 0; c < 4; ++c) {
            int c1 = c >> 1, c0 = c & 1;
            f2 cf = cmul_pk(c1 ? p6_1 : p6_0, (c1 ^ c0) ? V7b : V7a);
            f2 e0 = cmul_pk(cf, V4lo);
            f2 e1 = cmul_pk(cf, V4hi);
            *(uint2*)(TCb + sI*136 + (4*j + c)*8) = (uint2){pkh(e0), pkh(e1)};
        }
        // RF rows 4j..4j+3 (f16): RF[row] = V2[row2^row1]*V3[row1^row0]
        unsigned rr[4];
#pragma unroll
        for (int r = 0; r < 4; ++r) {
            int r1 = r >> 1, r0 = r & 1;
            f2 rf = cmul_pk(((j & 1) ^ r1) ? V2b : V2a, (r1 ^ r0) ? V3b : V3a);
            rr[r] = pkh(rf);
        }
        *(uint4*)(RFb + sI*64 + j*16) = (uint4){rr[0], rr[1], rr[2], rr[3]};
    }

    // ---- hoisted lane constants ----
    const int hq  = L >> 4;
    const int col = L & 15;
    const int th_t1 = hq >> 1, th_t2 = (hq >> 1) ^ (hq & 1);
    char* THl = THb + ((th_t1*2 + th_t2)*2 + (col & 1))*4;
    char* TCl = TCb + col*8;
    char* RFl = RFb + hq*16;

    char* wSr = Sb + col*32 + hq*8;     char* wSi = wSr + 512;
    char* rS  = Sb + col*32 + (hq & 1)*16 + (hq >> 1)*512;
    char* wM  = Mb + hq*320 + col*4;
    char* rM  = Mb + col*80 + (hq & 1)*32;
    char* Rw  = Rb + L*8;
    char* Rr  = Rb + (col & 7)*528 + hq*16;
    const unsigned selM = (hq >> 1) ? 0x07060302u : 0x05040100u;
    const f4 zz = {0.f, 0.f, 0.f, 0.f};

    for (int h = 0; h < 2; ++h) {
        for (int s8 = 0; s8 < 8; ++s8) {
            const int s = h*8 + s8;
            // ---- front-end: a_r = RF[4hq+r] * TH * TC[col][r&1] ----
            f2 u = h2f(*(const unsigned*)(THl + s*32));
            uint2 tc = *(const uint2*)(TCl + s*136);
            uint4 rf = *(const uint4*)(RFl + s*64);
            f2 g0 = cmul_pk(u, h2f(tc.x));
            f2 g1 = cmul_pk(u, h2f(tc.y));
            f2 a0 = cmul_pk(h2f(rf.x), g0);
            f2 a1 = cmul_pk(h2f(rf.y), g1);
            f2 a2 = cmul_pk(h2f(rf.z), g0);
            f2 a3 = cmul_pk(h2f(rf.w), g1);
            // ---- glue1: S -> LDS bf16, read B-frag ----
            unsigned r0 = __float_as_uint(a0.x)+0x8000u, r1 = __float_as_uint(a1.x)+0x8000u;
            unsigned r2 = __float_as_uint(a2.x)+0x8000u, r3 = __float_as_uint(a3.x)+0x8000u;
            unsigned i0 = __float_as_uint(a0.y)+0x8000u, i1 = __float_as_uint(a1.y)+0x8000u;
            unsigned i2 = __float_as_uint(a2.y)+0x8000u, i3 = __float_as_uint(a3.y)+0x8000u;
            uint2 pr = { __builtin_amdgcn_perm(r1, r0, 0x07060302u),
                         __builtin_amdgcn_perm(r3, r2, 0x07060302u) };
            uint2 pi = { __builtin_amdgcn_perm(i1, i0, 0x07060302u),
                         __builtin_amdgcn_perm(i3, i2, 0x07060302u) };
            *(uint2*)wSr = pr;
            *(uint2*)wSi = pi;
            short8 sfrag = *(short8*)rS;
            // ---- stage-1 MFMA: M = A * S ----
            f4 mr = __builtin_amdgcn_mfma_f32_16x16x32_bf16(A1f, sfrag, zz, 0, 0, 0);
            f4 mi = __builtin_amdgcn_mfma_f32_16x16x32_bf16(A2f, sfrag, zz, 0, 0, 0);
            // ---- glue2: M -> LDS (stride 80B), read A-frag ----
            unsigned m0 = __builtin_amdgcn_perm(__float_as_uint(mi[0])+0x8000u,
                                                __float_as_uint(mr[0])+0x8000u, 0x07060302u);
            unsigned m1 = __builtin_amdgcn_perm(__float_as_uint(mi[1])+0x8000u,
                                                __float_as_uint(mr[1])+0x8000u, 0x07060302u);
            unsigned m2 = __builtin_amdgcn_perm(__float_as_uint(mi[2])+0x8000u,
                                                __float_as_uint(mr[2])+0x8000u, 0x07060302u);
            unsigned m3 = __builtin_amdgcn_perm(__float_as_uint(mi[3])+0x8000u,
                                                __float_as_uint(mr[3])+0x8000u, 0x07060302u);
            *(unsigned*)(wM +   0) = m0;  *(unsigned*)(wM +  80) = m1;
            *(unsigned*)(wM + 160) = m2;  *(unsigned*)(wM + 240) = m3;
            uint4 da = *(uint4*)rM;
            uint4 db = *(uint4*)(rM + 16);
            uint4 nf;
            nf.x = __builtin_amdgcn_perm(da.y, da.x, selM);
            nf.y = __builtin_amdgcn_perm(da.w, da.z, selM);
            nf.z = __builtin_amdgcn_perm(db.y, db.x, selM);
            nf.w = __builtin_amdgcn_perm(db.w, db.z, selM);
            short8 nfrag;
            __builtin_memcpy(&nfrag, &nf, 16);
            // ---- stage-2 MFMA: phi = M * B^T ----
            f4 pr4 = __builtin_amdgcn_mfma_f32_16x16x32_bf16(nfrag, B1f, zz, 0, 0, 0);
            f4 pi4 = __builtin_amdgcn_mfma_f32_16x16x32_bf16(nfrag, B2f, zz, 0, 0, 0);
            // ---- probs + in-lane 4-WHT -> 3 classes -> R staging ----
            float Q0 = pr4[0]*pr4[0] + pi4[0]*pi4[0];
            float Q1 = pr4[1]*pr4[1] + pi4[1]*pi4[1];
            float Q2 = pr4[2]*pr4[2] + pi4[2]*pi4[2];
            float Q3 = pr4[3]*pr4[3] + pi4[3]*pi4[3];
            float s01 = Q0 + Q1, s23 = Q2 + Q3;
            float S00 = s01 + s23;
            float S10 = s01 - s23;
            float S11 = (Q0 - Q1) - (Q2 - Q3);
            auto h01 = __builtin_amdgcn_cvt_pkrtz(S00, S10);
            auto h23 = __builtin_amdgcn_cvt_pkrtz(S11, 0.f);
            uint2 wv;
            __builtin_memcpy(&wv.x, &h01, 4);
            __builtin_memcpy(&wv.y, &h23, 4);
            *(uint2*)(Rw + s8*528) = wv;
        }
        // ---- epilogue: out[s][w] = R x Sgn (8 chained f16 MFMAs) ----
        f4 acc = zz;
#pragma unroll
        for (int tt = 0; tt < 8; ++tt) {
            uint4 rv = *(uint4*)(Rr + tt*64);
            half8 af;
            __builtin_memcpy(&af, &rv, 16);
            acc = __builtin_amdgcn_mfma_f32_16x16x32_f16(af, sgt[tt*64 + L], acc, 0, 0, 0);
        }
        if (hq < 2 && col < 8) {
            size_t base = (size_t)(b0 + h*8 + hq*4) * 8 + col;
            out[base     ] = acc[0];
            out[base +  8] = acc[1];
            out[base + 16] = acc[2];
            out[base + 24] = acc[3];
        }
    }
}

extern "C" void kernel_launch(void* const* d_in, const int* in_sizes, int n_in,
                              void* d_out, int out_size, void* d_ws, size_t ws_size,
                              hipStream_t stream) {
    const float* x = (const float*)d_in[0];
    const float* w = (const float*)d_in[1];
    float* outp    = (float*)d_out;
    float* params  = (float*)d_ws;        // ~12.8 KB used
    int B = in_sizes[0] / 8;

    qnn_setup<<<1, 256, 0, stream>>>(w, params);
    int blocks = (B + 63) / 64;           // 4 waves/block, 16 samples/wave
    qnn_main<<<blocks, 256, 0, stream>>>(x, params, outp, B);
}

// Round 9
// 90.039 us; speedup vs baseline: 1.1201x; 1.0271x over previous
//
#include <hip/hip_runtime.h>
#include <math.h>

// QNN: 8 qubits, DIM=256, 2 entangling layers, B samples.
//  - RX(x_q) fuses with layer-1 RX -> product state v_q (V0,V1).
//  - CNOT ring 1 folded into product expansion; rank-8 split (R7):
//      S[row][col] = RF[row] * TH[(h1,h1^h0)][col0] * TC[col][r0]
//  - Layer-2 gates sample-independent: phi = A*S*B^T via 4x mfma 16x16x32 (R4).
//  - CNOT ring 2 + <Z_w> + cross-lane reduction folded into a constant sign
//    matrix applied as mfma f16 chain (R6).
// R9: all-f16 hot loop: packed v_pk_fma_f16 complex math on the f16 tables
//     (no f32<->f16 cvts, full-rate 2cyc), f16 MFMAs (finer mantissa than
//     bf16 -> absmax improves), glue1 = pure perms, glue2 = 4x cvt_pkrtz.
//     Epilogue every 4 samples -> 8192 B LDS/wave -> 5 blocks/CU (62.5% occ).

typedef float f2 __attribute__((ext_vector_type(2)));
typedef float f4 __attribute__((ext_vector_type(4)));
typedef _Float16 half8 __attribute__((ext_vector_type(8)));

// f32 complex mul, 2 VOP3P ops (verified R3-R8) - used in table-build phase
__device__ __forceinline__ f2 cmul_pk(f2 a, f2 b) {
    f2 t, d;
    asm("v_pk_mul_f32 %0, %1, %2 op_sel:[0,0] op_sel_hi:[0,1]"
        : "=v"(t) : "v"(a), "v"(b));
    asm("v_pk_fma_f32 %0, %1, %2, %3 op_sel:[1,1,0] op_sel_hi:[1,0,1] neg_lo:[1,0,0] neg_hi:[0,0,0]"
        : "=v"(d) : "v"(a), "v"(b), "v"(t));
    return d;
}
// packed-f16 complex mul: a,b = (re,im) f16x2 in one dword; 2 VOP3P ops
__device__ __forceinline__ unsigned cmulh(unsigned a, unsigned b) {
    unsigned t, d;
    asm("v_pk_mul_f16 %0, %1, %2 op_sel:[0,0] op_sel_hi:[0,1]"
        : "=v"(t) : "v"(a), "v"(b));                  // (ar*br, ar*bi)
    asm("v_pk_fma_f16 %0, %1, %2, %3 op_sel:[1,1,0] op_sel_hi:[1,0,1] neg_lo:[1,0,0] neg_hi:[0,0,0]"
        : "=v"(d) : "v"(a), "v"(b), "v"(t));          // (-ai*bi+, ai*br+)
    return d;
}
__device__ __forceinline__ unsigned pkh(f2 v) {
    auto pk = __builtin_amdgcn_cvt_pkrtz(v.x, v.y);
    unsigned u; __builtin_memcpy(&u, &pk, 4);
    return u;
}

// ---------------- setup ----------------
// d_ws: 0..511 floats (w0 + K-tables); 512..4607 A1/A2/B1/B2 f16 frag tables;
//       4608..12799 sign table (f16)
__global__ void qnn_setup(const float* __restrict__ w, float* __restrict__ p) {
    int t = threadIdx.x;
    if (t < 8) {
        int q = t;
        float cb = cosf(w[q*3+1]*0.5f), sb = sinf(w[q*3+1]*0.5f);
        float cg = cosf(w[q*3+2]*0.5f), sg = sinf(w[q*3+2]*0.5f);
        p[q] = w[q*3+0];
        float* K = p + 8 + q*8;
        K[0] = cg*cb;  K[1] = -sg*cb;      // K1
        K[2] = sg*sb;  K[3] = cg*sb;       // K2
        K[4] = cg*sb;  K[5] = sg*sb;       // K3
        K[6] = sg*cb;  K[7] = -cg*cb;      // K4
    }
    float G[8][2][2][2];
    for (int q = 0; q < 8; ++q) {
        const float* wq = w + (8+q)*3;
        float ca = cosf(wq[0]*0.5f), sa = sinf(wq[0]*0.5f);
        float cb = cosf(wq[1]*0.5f), sb = sinf(wq[1]*0.5f);
        float cg = cosf(wq[2]*0.5f), sg = sinf(wq[2]*0.5f);
        float A = cb*ca, Bv = sb*sa, C = sb*ca, D = cb*sa;
        float g00r = cg*A + sg*Bv, g00i = cg*Bv - sg*A;
        float g01r = -(cg*C + sg*D), g01i = sg*C - cg*D;
        G[q][0][0][0]=g00r;  G[q][0][0][1]=g00i;
        G[q][0][1][0]=g01r;  G[q][0][1][1]=g01i;
        G[q][1][0][0]=-g01r; G[q][1][0][1]=g01i;
        G[q][1][1][0]=g00r;  G[q][1][1][1]=-g00i;
    }
    int m = t & 15, k2 = t >> 4;
    float ar = 1.f, ai = 0.f, br = 1.f, bi = 0.f;
    for (int j = 0; j < 4; ++j) {
        int bm = (m >> (3-j)) & 1, bk = (k2 >> (3-j)) & 1;
        float gr = G[j][bm][bk][0],  gi = G[j][bm][bk][1];
        float nr = ar*gr - ai*gi, ni = ar*gi + ai*gr; ar = nr; ai = ni;
        float hr = G[4+j][bm][bk][0], hi = G[4+j][bm][bk][1];
        float mr = br*hr - bi*hi, mi = br*hi + bi*hr; br = mr; bi = mi;
    }
    _Float16* A1 = (_Float16*)((char*)p + 512);
    _Float16* A2 = A1 + 512;
    _Float16* B1 = A1 + 1024;
    _Float16* B2 = A1 + 1536;
    int p0 = ((k2 >> 3)*16 + m)*8 + (k2 & 7);
    int k3 = k2 + 16;
    int p1 = ((k3 >> 3)*16 + m)*8 + (k3 & 7);
    A1[p0] = (_Float16)ar;   A1[p1] = (_Float16)(-ai);
    A2[p0] = (_Float16)ai;   A2[p1] = (_Float16)ar;
    B1[p0] = (_Float16)br;   B1[p1] = (_Float16)(-bi);
    B2[p0] = (_Float16)bi;   B2[p1] = (_Float16)br;

    // sign table for the reduction GEMM (R6, verified)
    const int cls[8] = {2, 0, 1, 2, 2, 2, 2, 2};
    const int msk[8] = {31, 48, 48, 48, 56, 60, 62, 63};
    _Float16* SG = (_Float16*)((char*)p + 4608);
    for (int e = t; e < 512; e += 256) {
        int tt = e >> 6, l = e & 63, n = l & 15, quad = l >> 4;
        for (int j = 0; j < 8; ++j) {
            int k  = tt*32 + quad*8 + j;
            int Lp = k >> 2, c = k & 3;
            float v = 0.f;
            if (n < 8 && c == cls[n])
                v = (__popc(msk[n] & Lp) & 1) ? -1.f : 1.f;
            SG[e*8 + j] = (_Float16)v;
        }
    }
}

// per-wave LDS (8192 B total -> 32768/block -> 5 blocks/CU):
//   S 1024 | M 1280 | TH 512 | TC 2176 (stride 136) | RF 1024 (stride 64) |
//   R 2176 (4 rows x stride 544)
// VT (phase A, 2048 B) aliased into R region - dead before R writes.
#define WAVE_LDS 8192

__global__ __launch_bounds__(256, 5) void qnn_main(
        const float* __restrict__ x, const float* __restrict__ p,
        float* __restrict__ out, int B)
{
    __shared__ __align__(16) char smem[4 * WAVE_LDS];
    const int lane = threadIdx.x & 63;
    const int wid  = threadIdx.x >> 6;
    const int L = lane;
    const int b0 = (blockIdx.x * 4 + wid) * 16;
    if (b0 >= B) return;

    char* wb  = smem + wid * WAVE_LDS;
    char* Sb  = wb;
    char* Mb  = wb + 1024;
    char* THb = wb + 2304;
    char* TCb = wb + 2816;
    char* RFb = wb + 4992;
    char* Rb  = wb + 6016;              // R staging; VT aliased here first
    f4*   VT  = (f4*)Rb;

    // constant frags (loop-invariant), all f16
    const half8* fr = (const half8*)((const char*)p + 512);
    half8 A1f = fr[L], A2f = fr[64 + L], B1f = fr[128 + L], B2f = fr[192 + L];
    const half8* sgt = (const half8*)((const char*)p + 4608);

    // ---- phase A: build V for 16 samples x 8 qubits (2 builds/lane) ----
    {
        int sI = L >> 2, qp = (L & 3) * 2;
        float2 xv  = ((const float2*)x)[(size_t)(b0 + sI)*4 + (L & 3)];
        float2 w0p = ((const float2*)p)[qp >> 1];
        const f4* Kt = (const f4*)(p + 8);
#pragma unroll
        for (int u = 0; u < 2; ++u) {
            int q = qp + u;
            float ang = (u ? xv.y : xv.x) + (u ? w0p.y : w0p.x);
            float rev = ang * 0.07957747154594767f;      // (ang/2)/(2pi)
            float ca = __builtin_amdgcn_cosf(rev);
            float sa = __builtin_amdgcn_sinf(rev);
            f4 Ka = Kt[q*2], Kb = Kt[q*2+1];
            f4 v;
            v.x = ca*Ka.x + sa*Ka.z;  v.y = ca*Ka.y + sa*Ka.w;   // V0
            v.z = ca*Kb.x + sa*Kb.z;  v.w = ca*Kb.y + sa*Kb.w;   // V1
            VT[sI*8 + q] = v;
        }
    }
    // same-wave LDS is in-order; all regions per-wave -> no barriers

    // ---- phase B: build TH/TC/RF tables in f16 (4 lanes per sample) ----
    {
        int sI = L >> 2, j = L & 3;
        const f4* Vs = VT + sI*8;
        f4 q0v = Vs[0], q1v = Vs[1], q2v = Vs[2], q3v = Vs[3];
        f4 q4v = Vs[4], q5v = Vs[5], q6v = Vs[6], q7v = Vs[7];
        f2 V0a = {q0v.x,q0v.y}, V0b = {q0v.z,q0v.w};
        f2 V1a = {q1v.x,q1v.y}, V1b = {q1v.z,q1v.w};
        f2 V2a = {q2v.x,q2v.y}, V2b = {q2v.z,q2v.w};
        f2 V3a = {q3v.x,q3v.y}, V3b = {q3v.z,q3v.w};
        f2 V4a = {q4v.x,q4v.y}, V4b = {q4v.z,q4v.w};
        f2 V5a = {q5v.x,q5v.y}, V5b = {q5v.z,q5v.w};
        f2 V6a = {q6v.x,q6v.y}, V6b = {q6v.z,q6v.w};
        f2 V7a = {q7v.x,q7v.y}, V7b = {q7v.z,q7v.w};
        // TH slot j = (t1,t2) = (j>>1, j&1); entries col0 = 0,1  (f16)
        int t1 = j >> 1, t2 = j & 1;
        f2 th0 = cmul_pk(t1 ? V0b : V0a, t2 ? V1b : V1a);
        f2 th1 = cmul_pk(t1 ? V0a : V0b, t2 ? V1a : V1b);
        *(uint2*)(THb + sI*32 + j*8) = (uint2){pkh(th0), pkh(th1)};
        // TC cols 4j..4j+3 (f16): col3 = j>>1, col2 = j&1
        int col3 = j >> 1, col2 = j & 1;
        f2 v5s  = (col3 ^ col2) ? V5b : V5a;
        f2 p6_0 = cmul_pk(v5s, col2 ? V6b : V6a);     // col1 = 0
        f2 p6_1 = cmul_pk(v5s, col2 ? V6a : V6b);     // col1 = 1
        f2 V4lo = col3 ? V4b : V4a;                   // V4[col3]     (r0=0)
        f2 V4hi = col3 ? V4a : V4b;                   // V4[1^col3]   (r0=1)
#pragma unroll
        for (int c = 0; c < 4; ++c) {
            int c1 = c >> 1, c0 = c & 1;
            f2 cf = cmul_pk(c1 ? p6_1 : p6_0, (c1 ^ c0) ? V7b : V7a);
            f2 e0 = cmul_pk(cf, V4lo);
            f2 e1 = cmul_pk(cf, V4hi);
            *(uint2*)(TCb + sI*136 + (4*j + c)*8) = (uint2){pkh(e0), pkh(e1)};
        }
        // RF rows 4j..4j+3 (f16): RF[row] = V2[row2^row1]*V3[row1^row0]
        unsigned rr[4];
#pragma unroll
        for (int r = 0; r < 4; ++r) {
            int r1 = r >> 1, r0 = r & 1;
            f2 rf = cmul_pk(((j & 1) ^ r1) ? V2b : V2a, (r1 ^ r0) ? V3b : V3a);
            rr[r] = pkh(rf);
        }
        *(uint4*)(RFb + sI*64 + j*16) = (uint4){rr[0], rr[1], rr[2], rr[3]};
    }

    // ---- hoisted lane constants ----
    const int hq  = L >> 4;
    const int col = L & 15;
    const int th_t1 = hq >> 1, th_t2 = (hq >> 1) ^ (hq & 1);
    char* THl = THb + ((th_t1*2 + th_t2)*2 + (col & 1))*4;
    char* TCl = TCb + col*8;
    char* RFl = RFb + hq*16;

    char* wSr = Sb + col*32 + hq*8;     char* wSi = wSr + 512;
    char* rS  = Sb + col*32 + (hq & 1)*16 + (hq >> 1)*512;
    char* wM  = Mb + hq*320 + col*4;
    char* rM  = Mb + col*80 + (hq & 1)*32;
    char* Rw  = Rb + L*8;
    char* Rr  = Rb + (col & 3)*544 + hq*16;
    const unsigned selM = (hq >> 1) ? 0x07060302u : 0x05040100u;
    const f4 zz = {0.f, 0.f, 0.f, 0.f};

    for (int h = 0; h < 4; ++h) {
        for (int s4 = 0; s4 < 4; ++s4) {
            const int s = h*4 + s4;
            // ---- front-end (all f16): a_r = RF[4hq+r] * TH * TC[col][r&1] ----
            unsigned u = *(const unsigned*)(THl + s*32);
            uint2 tc = *(const uint2*)(TCl + s*136);
            uint4 rf = *(const uint4*)(RFl + s*64);
            unsigned g0 = cmulh(u, tc.x);
            unsigned g1 = cmulh(u, tc.y);
            unsigned a0 = cmulh(rf.x, g0);
            unsigned a1 = cmulh(rf.y, g1);
            unsigned a2 = cmulh(rf.z, g0);
            unsigned a3 = cmulh(rf.w, g1);
            // ---- glue1: split (re,im) dwords -> Sr/Si rows, pure perms ----
            uint2 pr = { __builtin_amdgcn_perm(a1, a0, 0x05040100u),
                         __builtin_amdgcn_perm(a3, a2, 0x05040100u) };
            uint2 pi = { __builtin_amdgcn_perm(a1, a0, 0x07060302u),
                         __builtin_amdgcn_perm(a3, a2, 0x07060302u) };
            *(uint2*)wSr = pr;
            *(uint2*)wSi = pi;
            half8 sfrag = *(half8*)rS;
            // ---- stage-1 MFMA (f16): M = A * S ----
            f4 mr = __builtin_amdgcn_mfma_f32_16x16x32_f16(A1f, sfrag, zz, 0, 0, 0);
            f4 mi = __builtin_amdgcn_mfma_f32_16x16x32_f16(A2f, sfrag, zz, 0, 0, 0);
            // ---- glue2: pack (Mr,Mi) f16 pairs, LDS transpose, read A-frag --
            *(unsigned*)(wM +   0) = pkh((f2){mr[0], mi[0]});
            *(unsigned*)(wM +  80) = pkh((f2){mr[1], mi[1]});
            *(unsigned*)(wM + 160) = pkh((f2){mr[2], mi[2]});
            *(unsigned*)(wM + 240) = pkh((f2){mr[3], mi[3]});
            uint4 da = *(uint4*)rM;
            uint4 db = *(uint4*)(rM + 16);
            uint4 nf;
            nf.x = __builtin_amdgcn_perm(da.y, da.x, selM);
            nf.y = __builtin_amdgcn_perm(da.w, da.z, selM);
            nf.z = __builtin_amdgcn_perm(db.y, db.x, selM);
            nf.w = __builtin_amdgcn_perm(db.w, db.z, selM);
            half8 nfrag;
            __builtin_memcpy(&nfrag, &nf, 16);
            // ---- stage-2 MFMA (f16): phi = M * B^T ----
            f4 pr4 = __builtin_amdgcn_mfma_f32_16x16x32_f16(nfrag, B1f, zz, 0, 0, 0);
            f4 pi4 = __builtin_amdgcn_mfma_f32_16x16x32_f16(nfrag, B2f, zz, 0, 0, 0);
            // ---- probs + in-lane 4-WHT -> 3 classes -> R staging ----
            float Q0 = pr4[0]*pr4[0] + pi4[0]*pi4[0];
            float Q1 = pr4[1]*pr4[1] + pi4[1]*pi4[1];
            float Q2 = pr4[2]*pr4[2] + pi4[2]*pi4[2];
            float Q3 = pr4[3]*pr4[3] + pi4[3]*pi4[3];
            float s01 = Q0 + Q1, s23 = Q2 + Q3;
            float S00 = s01 + s23;
            float S10 = s01 - s23;
            float S11 = (Q0 - Q1) - (Q2 - Q3);
            uint2 wv = { pkh((f2){S00, S10}), pkh((f2){S11, 0.f}) };
            *(uint2*)(Rw + s4*544) = wv;
        }
        // ---- epilogue: out[s][w] = R x Sgn (8 chained f16 MFMAs) ----
        f4 acc = zz;
#pragma unroll
        for (int tt = 0; tt < 8; ++tt) {
            uint4 rv = *(uint4*)(Rr + tt*64);
            half8 af;
            __builtin_memcpy(&af, &rv, 16);
            acc = __builtin_amdgcn_mfma_f32_16x16x32_f16(af, sgt[tt*64 + L], acc, 0, 0, 0);
        }
        if (hq == 0 && col < 8) {       // rows 0..3 = samples h*4..h*4+3
            size_t base = (size_t)(b0 + h*4) * 8 + col;
            out[base     ] = acc[0];
            out[base +  8] = acc[1];
            out[base + 16] = acc[2];
            out[base + 24] = acc[3];
        }
    }
}

extern "C" void kernel_launch(void* const* d_in, const int* in_sizes, int n_in,
                              void* d_out, int out_size, void* d_ws, size_t ws_size,
                              hipStream_t stream) {
    const float* x = (const float*)d_in[0];
    const float* w = (const float*)d_in[1];
    float* outp    = (float*)d_out;
    float* params  = (float*)d_ws;        // ~12.8 KB used
    int B = in_sizes[0] / 8;

    qnn_setup<<<1, 256, 0, stream>>>(w, params);
    int blocks = (B + 63) / 64;           // 4 waves/block, 16 samples/wave
    qnn_main<<<blocks, 256, 0, stream>>>(x, params, outp, B);
}

// Round 11
// 87.907 us; speedup vs baseline: 1.1472x; 1.0242x over previous
//
#include <hip/hip_runtime.h>
#include <math.h>

// QNN: 8 qubits, DIM=256, 2 entangling layers, B samples.
//  - RX(x_q) fuses with layer-1 RX -> product state v_q (V0,V1).
//  - CNOT ring 1 folded into product expansion; rank-8 split (R7):
//      S[row][col] = RF[row] * TH[(h1,h1^h0)][col0] * cf[col] * V4[col3^r0]
//  - Layer-2 gates sample-independent: phi = A*S*B^T via 4x mfma 16x16x32 f16.
//  - CNOT ring 2 + <Z_w> + cross-lane reduction folded into a constant sign
//    matrix applied as mfma f16 chain (R6).
// R11 = R10 with the S-read index fix: lane hq reads stacked k-rows
//   hq*8..hq*8+7 of [Sr;Si] -> offset (hq&1)*32 + (hq>>1)*8 (chunk pair by
//   LOW bit, Sr/Si half by HIGH bit). R10 had the two swapped -> wrong S.
//   S staging: stride 80B, quad-interleaved [Sr_quad|Si_quad] 16B chunks;
//   glue1 = 1x b128 write + paired b64 reads (<=2-way banks, free).

typedef float f2 __attribute__((ext_vector_type(2)));
typedef float f4 __attribute__((ext_vector_type(4)));
typedef _Float16 half8 __attribute__((ext_vector_type(8)));

// f32 complex mul, 2 VOP3P ops (verified R3-R9) - table-build phase
__device__ __forceinline__ f2 cmul_pk(f2 a, f2 b) {
    f2 t, d;
    asm("v_pk_mul_f32 %0, %1, %2 op_sel:[0,0] op_sel_hi:[0,1]"
        : "=v"(t) : "v"(a), "v"(b));
    asm("v_pk_fma_f32 %0, %1, %2, %3 op_sel:[1,1,0] op_sel_hi:[1,0,1] neg_lo:[1,0,0] neg_hi:[0,0,0]"
        : "=v"(d) : "v"(a), "v"(b), "v"(t));
    return d;
}
// packed-f16 complex mul (verified R9)
__device__ __forceinline__ unsigned cmulh(unsigned a, unsigned b) {
    unsigned t, d;
    asm("v_pk_mul_f16 %0, %1, %2 op_sel:[0,0] op_sel_hi:[0,1]"
        : "=v"(t) : "v"(a), "v"(b));
    asm("v_pk_fma_f16 %0, %1, %2, %3 op_sel:[1,1,0] op_sel_hi:[1,0,1] neg_lo:[1,0,0] neg_hi:[0,0,0]"
        : "=v"(d) : "v"(a), "v"(b), "v"(t));
    return d;
}
__device__ __forceinline__ unsigned pkh(f2 v) {
    auto pk = __builtin_amdgcn_cvt_pkrtz(v.x, v.y);
    unsigned u; __builtin_memcpy(&u, &pk, 4);
    return u;
}

// ---------------- setup (identical to R9/R10) ----------------
__global__ void qnn_setup(const float* __restrict__ w, float* __restrict__ p) {
    int t = threadIdx.x;
    if (t < 8) {
        int q = t;
        float cb = cosf(w[q*3+1]*0.5f), sb = sinf(w[q*3+1]*0.5f);
        float cg = cosf(w[q*3+2]*0.5f), sg = sinf(w[q*3+2]*0.5f);
        p[q] = w[q*3+0];
        float* K = p + 8 + q*8;
        K[0] = cg*cb;  K[1] = -sg*cb;      // K1
        K[2] = sg*sb;  K[3] = cg*sb;       // K2
        K[4] = cg*sb;  K[5] = sg*sb;       // K3
        K[6] = sg*cb;  K[7] = -cg*cb;      // K4
    }
    float G[8][2][2][2];
    for (int q = 0; q < 8; ++q) {
        const float* wq = w + (8+q)*3;
        float ca = cosf(wq[0]*0.5f), sa = sinf(wq[0]*0.5f);
        float cb = cosf(wq[1]*0.5f), sb = sinf(wq[1]*0.5f);
        float cg = cosf(wq[2]*0.5f), sg = sinf(wq[2]*0.5f);
        float A = cb*ca, Bv = sb*sa, C = sb*ca, D = cb*sa;
        float g00r = cg*A + sg*Bv, g00i = cg*Bv - sg*A;
        float g01r = -(cg*C + sg*D), g01i = sg*C - cg*D;
        G[q][0][0][0]=g00r;  G[q][0][0][1]=g00i;
        G[q][0][1][0]=g01r;  G[q][0][1][1]=g01i;
        G[q][1][0][0]=-g01r; G[q][1][0][1]=g01i;
        G[q][1][1][0]=g00r;  G[q][1][1][1]=-g00i;
    }
    int m = t & 15, k2 = t >> 4;
    float ar = 1.f, ai = 0.f, br = 1.f, bi = 0.f;
    for (int j = 0; j < 4; ++j) {
        int bm = (m >> (3-j)) & 1, bk = (k2 >> (3-j)) & 1;
        float gr = G[j][bm][bk][0],  gi = G[j][bm][bk][1];
        float nr = ar*gr - ai*gi, ni = ar*gi + ai*gr; ar = nr; ai = ni;
        float hr = G[4+j][bm][bk][0], hi = G[4+j][bm][bk][1];
        float mr = br*hr - bi*hi, mi = br*hi + bi*hr; br = mr; bi = mi;
    }
    _Float16* A1 = (_Float16*)((char*)p + 512);
    _Float16* A2 = A1 + 512;
    _Float16* B1 = A1 + 1024;
    _Float16* B2 = A1 + 1536;
    int p0 = ((k2 >> 3)*16 + m)*8 + (k2 & 7);
    int k3 = k2 + 16;
    int p1 = ((k3 >> 3)*16 + m)*8 + (k3 & 7);
    A1[p0] = (_Float16)ar;   A1[p1] = (_Float16)(-ai);
    A2[p0] = (_Float16)ai;   A2[p1] = (_Float16)ar;
    B1[p0] = (_Float16)br;   B1[p1] = (_Float16)(-bi);
    B2[p0] = (_Float16)bi;   B2[p1] = (_Float16)br;

    // sign table for the reduction GEMM (R6, verified)
    const int cls[8] = {2, 0, 1, 2, 2, 2, 2, 2};
    const int msk[8] = {31, 48, 48, 48, 56, 60, 62, 63};
    _Float16* SG = (_Float16*)((char*)p + 4608);
    for (int e = t; e < 512; e += 256) {
        int tt = e >> 6, l = e & 63, n = l & 15, quad = l >> 4;
        for (int j = 0; j < 8; ++j) {
            int k  = tt*32 + quad*8 + j;
            int Lp = k >> 2, c = k & 3;
            float v = 0.f;
            if (n < 8 && c == cls[n])
                v = (__popc(msk[n] & Lp) & 1) ? -1.f : 1.f;
            SG[e*8 + j] = (_Float16)v;
        }
    }
}

// per-wave LDS (7616 B used, 8192 budget -> 32768/block -> 5 blocks/CU):
//   S 1280 (16 cols x 80B, chunks [Sr_quad 8B|Si_quad 8B]) | M 1280 (str 80) |
//   TH 512 | cf 1088 (stride 68) | V4 256 | RF 1024 (stride 64) |
//   R 2176 (4 rows x 544)  [VT 2048 aliased into R, dead before R writes]
#define WAVE_LDS 8192

__global__ __launch_bounds__(256, 5) void qnn_main(
        const float* __restrict__ x, const float* __restrict__ p,
        float* __restrict__ out, int B)
{
    __shared__ __align__(16) char smem[4 * WAVE_LDS];
    const int lane = threadIdx.x & 63;
    const int wid  = threadIdx.x >> 6;
    const int L = lane;
    const int b0 = (blockIdx.x * 4 + wid) * 16;
    if (b0 >= B) return;

    char* wb  = smem + wid * WAVE_LDS;
    char* Sb  = wb;                     // 1280
    char* Mb  = wb + 1280;              // 1280
    char* THb = wb + 2560;              // 512
    char* CFb = wb + 3072;              // 1088
    char* V4t = wb + 4160;              // 256
    char* RFb = wb + 4416;              // 1024
    char* Rb  = wb + 5440;              // 2176 (VT alias first)
    f4*   VT  = (f4*)Rb;

    // constant frags (loop-invariant), all f16
    const half8* fr = (const half8*)((const char*)p + 512);
    half8 A1f = fr[L], A2f = fr[64 + L], B1f = fr[128 + L], B2f = fr[192 + L];
    const half8* sgt = (const half8*)((const char*)p + 4608);

    // ---- phase A: build V for 16 samples x 8 qubits (2 builds/lane) ----
    {
        int sI = L >> 2, qp = (L & 3) * 2;
        float2 xv  = ((const float2*)x)[(size_t)(b0 + sI)*4 + (L & 3)];
        float2 w0p = ((const float2*)p)[qp >> 1];
        const f4* Kt = (const f4*)(p + 8);
#pragma unroll
        for (int u = 0; u < 2; ++u) {
            int q = qp + u;
            float ang = (u ? xv.y : xv.x) + (u ? w0p.y : w0p.x);
            float rev = ang * 0.07957747154594767f;      // (ang/2)/(2pi)
            float ca = __builtin_amdgcn_cosf(rev);
            float sa = __builtin_amdgcn_sinf(rev);
            f4 Ka = Kt[q*2], Kb = Kt[q*2+1];
            f4 v;
            v.x = ca*Ka.x + sa*Ka.z;  v.y = ca*Ka.y + sa*Ka.w;   // V0
            v.z = ca*Kb.x + sa*Kb.z;  v.w = ca*Kb.y + sa*Kb.w;   // V1
            VT[sI*8 + q] = v;
        }
    }
    // same-wave LDS is in-order; all regions per-wave -> no barriers

    // ---- phase B: build TH/cf/V4/RF tables in f16 (4 lanes per sample) ----
    {
        int sI = L >> 2, j = L & 3;
        const f4* Vs = VT + sI*8;
        f4 q0v = Vs[0], q1v = Vs[1], q2v = Vs[2], q3v = Vs[3];
        f4 q4v = Vs[4], q5v = Vs[5], q6v = Vs[6], q7v = Vs[7];
        f2 V0a = {q0v.x,q0v.y}, V0b = {q0v.z,q0v.w};
        f2 V1a = {q1v.x,q1v.y}, V1b = {q1v.z,q1v.w};
        f2 V2a = {q2v.x,q2v.y}, V2b = {q2v.z,q2v.w};
        f2 V3a = {q3v.x,q3v.y}, V3b = {q3v.z,q3v.w};
        f2 V4a = {q4v.x,q4v.y}, V4bv = {q4v.z,q4v.w};
        f2 V5a = {q5v.x,q5v.y}, V5b = {q5v.z,q5v.w};
        f2 V6a = {q6v.x,q6v.y}, V6b = {q6v.z,q6v.w};
        f2 V7a = {q7v.x,q7v.y}, V7b = {q7v.z,q7v.w};
        // TH slot j = (t1,t2) = (j>>1, j&1); entries col0 = 0,1  (f16)
        int t1 = j >> 1, t2 = j & 1;
        f2 th0 = cmul_pk(t1 ? V0b : V0a, t2 ? V1b : V1a);
        f2 th1 = cmul_pk(t1 ? V0a : V0b, t2 ? V1a : V1b);
        *(uint2*)(THb + sI*32 + j*8) = (uint2){pkh(th0), pkh(th1)};
        // cf for cols 4j..4j+3 (f16): col3 = j>>1, col2 = j&1
        int col3 = j >> 1, col2 = j & 1;
        f2 v5s  = (col3 ^ col2) ? V5b : V5a;
        f2 p6_0 = cmul_pk(v5s, col2 ? V6b : V6a);     // col1 = 0
        f2 p6_1 = cmul_pk(v5s, col2 ? V6a : V6b);     // col1 = 1
#pragma unroll
        for (int c = 0; c < 4; ++c) {
            int c1 = c >> 1, c0 = c & 1;
            f2 cf = cmul_pk(c1 ? p6_1 : p6_0, (c1 ^ c0) ? V7b : V7a);
            *(unsigned*)(CFb + sI*68 + (4*j + c)*4) = pkh(cf);
        }
        // V4 table: entry[col3] = (V4[col3], V4[1^col3])  (j<2 writes)
        if (j < 2) {
            f2 lo = j ? V4bv : V4a, hi = j ? V4a : V4bv;
            *(uint2*)(V4t + sI*16 + j*8) = (uint2){pkh(lo), pkh(hi)};
        }
        // RF rows 4j..4j+3 (f16): RF[row] = V2[row2^row1]*V3[row1^row0]
        unsigned rr[4];
#pragma unroll
        for (int r = 0; r < 4; ++r) {
            int r1 = r >> 1, r0 = r & 1;
            f2 rf = cmul_pk(((j & 1) ^ r1) ? V2b : V2a, (r1 ^ r0) ? V3b : V3a);
            rr[r] = pkh(rf);
        }
        *(uint4*)(RFb + sI*64 + j*16) = (uint4){rr[0], rr[1], rr[2], rr[3]};
    }

    // ---- hoisted lane constants ----
    const int hq  = L >> 4;
    const int col = L & 15;
    const int th_t1 = hq >> 1, th_t2 = (hq >> 1) ^ (hq & 1);
    char* THl = THb + ((th_t1*2 + th_t2)*2 + (col & 1))*4;
    char* CFl = CFb + col*4;
    char* V4l = V4t + (col >> 3)*8;
    char* RFl = RFb + hq*16;

    char* wS  = Sb + col*80 + hq*16;                    // [Sr_quad | Si_quad]
    // read k-rows hq*8..hq*8+7 of stacked [Sr;Si]:
    //   chunk pair by LOW bit of hq, Sr/Si half by HIGH bit (R10 had these
    //   swapped -> wrong S matrix; fixed here)
    char* rS  = Sb + col*80 + (hq & 1)*32 + (hq >> 1)*8;
    char* wM  = Mb + hq*320 + col*4;
    char* rM  = Mb + col*80 + (hq & 1)*32;
    char* Rw  = Rb + L*8;
    char* Rr  = Rb + (col & 3)*544 + hq*16;
    const unsigned selM = (hq >> 1) ? 0x07060302u : 0x05040100u;
    const f4 zz = {0.f, 0.f, 0.f, 0.f};

    for (int h = 0; h < 4; ++h) {
        for (int s4 = 0; s4 < 4; ++s4) {
            const int s = h*4 + s4;
            // ---- front-end (all f16): a_r = RF * TH * cf * V4[r&1 sel] ----
            unsigned u  = *(const unsigned*)(THl + s*32);
            unsigned cf = *(const unsigned*)(CFl + s*68);
            uint2   v4  = *(const uint2*)(V4l + s*16);
            uint4   rf  = *(const uint4*)(RFl + s*64);
            unsigned g  = cmulh(u, cf);
            unsigned gl = cmulh(g, v4.x);
            unsigned gh = cmulh(g, v4.y);
            unsigned a0 = cmulh(rf.x, gl);
            unsigned a1 = cmulh(rf.y, gh);
            unsigned a2 = cmulh(rf.z, gl);
            unsigned a3 = cmulh(rf.w, gh);
            // ---- glue1: one b128 chunk write, paired b64 reads ----
            uint2 pr = { __builtin_amdgcn_perm(a1, a0, 0x05040100u),
                         __builtin_amdgcn_perm(a3, a2, 0x05040100u) };
            uint2 pi = { __builtin_amdgcn_perm(a1, a0, 0x07060302u),
                         __builtin_amdgcn_perm(a3, a2, 0x07060302u) };
            *(uint4*)wS = (uint4){pr.x, pr.y, pi.x, pi.y};
            uint2 lo = *(uint2*)rS;
            uint2 hi = *(uint2*)(rS + 16);
            uint4 sv = {lo.x, lo.y, hi.x, hi.y};
            half8 sfrag;
            __builtin_memcpy(&sfrag, &sv, 16);
            // ---- stage-1 MFMA (f16): M = A * S ----
            f4 mr = __builtin_amdgcn_mfma_f32_16x16x32_f16(A1f, sfrag, zz, 0, 0, 0);
            f4 mi = __builtin_amdgcn_mfma_f32_16x16x32_f16(A2f, sfrag, zz, 0, 0, 0);
            // ---- glue2: pack (Mr,Mi) f16 pairs, LDS transpose, read A-frag --
            *(unsigned*)(wM +   0) = pkh((f2){mr[0], mi[0]});
            *(unsigned*)(wM +  80) = pkh((f2){mr[1], mi[1]});
            *(unsigned*)(wM + 160) = pkh((f2){mr[2], mi[2]});
            *(unsigned*)(wM + 240) = pkh((f2){mr[3], mi[3]});
            uint4 da = *(uint4*)rM;
            uint4 db = *(uint4*)(rM + 16);
            uint4 nf;
            nf.x = __builtin_amdgcn_perm(da.y, da.x, selM);
            nf.y = __builtin_amdgcn_perm(da.w, da.z, selM);
            nf.z = __builtin_amdgcn_perm(db.y, db.x, selM);
            nf.w = __builtin_amdgcn_perm(db.w, db.z, selM);
            half8 nfrag;
            __builtin_memcpy(&nfrag, &nf, 16);
            // ---- stage-2 MFMA (f16): phi = M * B^T ----
            f4 pr4 = __builtin_amdgcn_mfma_f32_16x16x32_f16(nfrag, B1f, zz, 0, 0, 0);
            f4 pi4 = __builtin_amdgcn_mfma_f32_16x16x32_f16(nfrag, B2f, zz, 0, 0, 0);
            // ---- probs + in-lane 4-WHT -> 3 classes -> R staging ----
            float Q0 = pr4[0]*pr4[0] + pi4[0]*pi4[0];
            float Q1 = pr4[1]*pr4[1] + pi4[1]*pi4[1];
            float Q2 = pr4[2]*pr4[2] + pi4[2]*pi4[2];
            float Q3 = pr4[3]*pr4[3] + pi4[3]*pi4[3];
            float s01 = Q0 + Q1, s23 = Q2 + Q3;
            float S00 = s01 + s23;
            float S10 = s01 - s23;
            float S11 = (Q0 - Q1) - (Q2 - Q3);
            uint2 wv = { pkh((f2){S00, S10}), pkh((f2){S11, 0.f}) };
            *(uint2*)(Rw + s4*544) = wv;
        }
        // ---- epilogue: out[s][w] = R x Sgn (8 chained f16 MFMAs) ----
        f4 acc = zz;
#pragma unroll
        for (int tt = 0; tt < 8; ++tt) {
            uint4 rv = *(uint4*)(Rr + tt*64);
            half8 af;
            __builtin_memcpy(&af, &rv, 16);
            acc = __builtin_amdgcn_mfma_f32_16x16x32_f16(af, sgt[tt*64 + L], acc, 0, 0, 0);
        }
        if (hq == 0 && col < 8) {       // rows 0..3 = samples h*4..h*4+3
            size_t base = (size_t)(b0 + h*4) * 8 + col;
            out[base     ] = acc[0];
            out[base +  8] = acc[1];
            out[base + 16] = acc[2];
            out[base + 24] = acc[3];
        }
    }
}

extern "C" void kernel_launch(void* const* d_in, const int* in_sizes, int n_in,
                              void* d_out, int out_size, void* d_ws, size_t ws_size,
                              hipStream_t stream) {
    const float* x = (const float*)d_in[0];
    const float* w = (const float*)d_in[1];
    float* outp    = (float*)d_out;
    float* params  = (float*)d_ws;        // ~12.8 KB used
    int B = in_sizes[0] / 8;

    qnn_setup<<<1, 256, 0, stream>>>(w, params);
    int blocks = (B + 63) / 64;           // 4 waves/block, 16 samples/wave
    qnn_main<<<blocks, 256, 0, stream>>>(x, params, outp, B);
}

// Round 12
// 83.891 us; speedup vs baseline: 1.2022x; 1.0479x over previous
//
#include <hip/hip_runtime.h>
#include <math.h>

// QNN: 8 qubits, DIM=256, 2 entangling layers, B samples.
//  - RX(x_q) fuses with layer-1 RX -> product state v_q (V0,V1).
//  - CNOT ring 1 folded into product expansion; rank-8 split (R7):
//      S[row][col] = RF[row] * TH[(h1,h1^h0)][col0] * cf[col] * V4[col3^r0]
//  - Layer-2: phi = A*S*B^T. R12: computed as T = S^T*A^T (= M^T) then
//    phi^T = B*T, using mfma_f32_16x16x16f16 (K=16) whose A/B operand layout
//    (idx=lane&15, k=quad*4+j) EQUALS the C/D layout (row=quad*4+r,col=lane&15):
//    -> front-end a0..a3 feeds stage-1 A-operand directly (no S staging),
//    -> stage-1 C output feeds stage-2 B-operand directly (no M staging).
//    Complex = 4 real MFMAs per stage. Zero LDS round-trips in the matmul.
//  - CNOT ring 2 + <Z_w> + reduction folded into a constant sign matrix
//    applied as mfma 16x16x32 f16 chain (R6). phi^T output remaps lane/class
//    bits: cls={2,0,0,0,0,0,1,2}, msk={55,12,14,15,47,63,63,63}
//    (wires0-3 -> col, wires4,5 -> quad, wires6,7 -> in-lane r).

typedef float f2 __attribute__((ext_vector_type(2)));
typedef float f4 __attribute__((ext_vector_type(4)));
typedef _Float16 half4 __attribute__((ext_vector_type(4)));
typedef _Float16 half8 __attribute__((ext_vector_type(8)));

// f32 complex mul, 2 VOP3P ops (verified R3-R11) - table-build phase
__device__ __forceinline__ f2 cmul_pk(f2 a, f2 b) {
    f2 t, d;
    asm("v_pk_mul_f32 %0, %1, %2 op_sel:[0,0] op_sel_hi:[0,1]"
        : "=v"(t) : "v"(a), "v"(b));
    asm("v_pk_fma_f32 %0, %1, %2, %3 op_sel:[1,1,0] op_sel_hi:[1,0,1] neg_lo:[1,0,0] neg_hi:[0,0,0]"
        : "=v"(d) : "v"(a), "v"(b), "v"(t));
    return d;
}
// packed-f16 complex mul (verified R9-R11)
__device__ __forceinline__ unsigned cmulh(unsigned a, unsigned b) {
    unsigned t, d;
    asm("v_pk_mul_f16 %0, %1, %2 op_sel:[0,0] op_sel_hi:[0,1]"
        : "=v"(t) : "v"(a), "v"(b));
    asm("v_pk_fma_f16 %0, %1, %2, %3 op_sel:[1,1,0] op_sel_hi:[1,0,1] neg_lo:[1,0,0] neg_hi:[0,0,0]"
        : "=v"(d) : "v"(a), "v"(b), "v"(t));
    return d;
}
__device__ __forceinline__ unsigned pkh(f2 v) {
    auto pk = __builtin_amdgcn_cvt_pkrtz(v.x, v.y);
    unsigned u; __builtin_memcpy(&u, &pk, 4);
    return u;
}
__device__ __forceinline__ half4 h4(uint2 u) {
    half4 h; __builtin_memcpy(&h, &u, 8);
    return h;
}
__device__ __forceinline__ f4 mfma16(half4 a, half4 b, f4 c) {
    return __builtin_amdgcn_mfma_f32_16x16x16f16(a, b, c, 0, 0, 0);
}

// ---------------- setup ----------------
// d_ws bytes: 0..511 floats (w0 + K-tables);
//   512: S1Ar | 1024: S1Ai | 1536: S1nAi   (A^T in 16x16x16 B-layout, f16)
//   2048: S2Br | 2560: S2Bi | 3072: S2nBi  (B   in 16x16x16 A-layout, f16)
//   4608..12799: sign table SG (f16, 16x16x32 A-layout chunks)
__global__ void qnn_setup(const float* __restrict__ w, float* __restrict__ p) {
    int t = threadIdx.x;
    if (t < 8) {
        int q = t;
        float cb = cosf(w[q*3+1]*0.5f), sb = sinf(w[q*3+1]*0.5f);
        float cg = cosf(w[q*3+2]*0.5f), sg = sinf(w[q*3+2]*0.5f);
        p[q] = w[q*3+0];
        float* K = p + 8 + q*8;
        K[0] = cg*cb;  K[1] = -sg*cb;      // K1
        K[2] = sg*sb;  K[3] = cg*sb;       // K2
        K[4] = cg*sb;  K[5] = sg*sb;       // K3
        K[6] = sg*cb;  K[7] = -cg*cb;      // K4
    }
    float G[8][2][2][2];
    for (int q = 0; q < 8; ++q) {
        const float* wq = w + (8+q)*3;
        float ca = cosf(wq[0]*0.5f), sa = sinf(wq[0]*0.5f);
        float cb = cosf(wq[1]*0.5f), sb = sinf(wq[1]*0.5f);
        float cg = cosf(wq[2]*0.5f), sg = sinf(wq[2]*0.5f);
        float A = cb*ca, Bv = sb*sa, C = sb*ca, D = cb*sa;
        float g00r = cg*A + sg*Bv, g00i = cg*Bv - sg*A;
        float g01r = -(cg*C + sg*D), g01i = sg*C - cg*D;
        G[q][0][0][0]=g00r;  G[q][0][0][1]=g00i;
        G[q][0][1][0]=g01r;  G[q][0][1][1]=g01i;
        G[q][1][0][0]=-g01r; G[q][1][0][1]=g01i;
        G[q][1][1][0]=g00r;  G[q][1][1][1]=-g00i;
    }
    int m = t & 15, k2 = t >> 4;
    float ar = 1.f, ai = 0.f, br = 1.f, bi = 0.f;
    for (int j = 0; j < 4; ++j) {
        int bm = (m >> (3-j)) & 1, bk = (k2 >> (3-j)) & 1;
        float gr = G[j][bm][bk][0],  gi = G[j][bm][bk][1];
        float nr = ar*gr - ai*gi, ni = ar*gi + ai*gr; ar = nr; ai = ni;
        float hr = G[4+j][bm][bk][0], hi = G[4+j][bm][bk][1];
        float mr = br*hr - bi*hi, mi = br*hi + bi*hr; br = mr; bi = mi;
    }
    // element A[m][k2] -> lane l=(k2>>2)*16+m, slot j=k2&3 (same for both
    // the B-layout of A^T and the A-layout of B: idx=lane&15, k=quad*4+j)
    _Float16* S1Ar  = (_Float16*)((char*)p +  512);
    _Float16* S1Ai  = (_Float16*)((char*)p + 1024);
    _Float16* S1nAi = (_Float16*)((char*)p + 1536);
    _Float16* S2Br  = (_Float16*)((char*)p + 2048);
    _Float16* S2Bi  = (_Float16*)((char*)p + 2560);
    _Float16* S2nBi = (_Float16*)((char*)p + 3072);
    int idx = ((k2 >> 2)*16 + m)*4 + (k2 & 3);
    S1Ar[idx]  = (_Float16)ar;
    S1Ai[idx]  = (_Float16)ai;
    S1nAi[idx] = (_Float16)(-ai);
    S2Br[idx]  = (_Float16)br;
    S2Bi[idx]  = (_Float16)bi;
    S2nBi[idx] = (_Float16)(-bi);

    // sign table for the reduction GEMM - phi^T bit assignment:
    // lane = quad*16+col: col = wires0-3 index (wire0 MSB), quad = wires4,5;
    // in-lane r = wires6,7. Classes: c0=S00, c1=S10 (sign w6), c2=S11 (w6^w7).
    const int cls[8] = {2, 0, 0, 0, 0, 0, 1, 2};
    const int msk[8] = {55, 12, 14, 15, 47, 63, 63, 63};
    _Float16* SG = (_Float16*)((char*)p + 4608);
    for (int e = t; e < 512; e += 256) {
        int tt = e >> 6, l = e & 63, n = l & 15, quad = l >> 4;
        for (int j = 0; j < 8; ++j) {
            int k  = tt*32 + quad*8 + j;
            int Lp = k >> 2, c = k & 3;
            float v = 0.f;
            if (n < 8 && c == cls[n])
                v = (__popc(msk[n] & Lp) & 1) ? -1.f : 1.f;
            SG[e*8 + j] = (_Float16)v;
        }
    }
}

// per-wave LDS (5056 B used -> 5120; block 20480 -> 7 blocks/CU by LDS):
//   TH 512 | cf 1088 (stride 68) | V4 256 | RF 1024 (stride 64) |
//   R 2176 (4 rows x 544)  [VT 2048 aliased into R, dead before R writes]
#define WAVE_LDS 5120

__global__ __launch_bounds__(256, 6) void qnn_main(
        const float* __restrict__ x, const float* __restrict__ p,
        float* __restrict__ out, int B)
{
    __shared__ __align__(16) char smem[4 * WAVE_LDS];
    const int lane = threadIdx.x & 63;
    const int wid  = threadIdx.x >> 6;
    const int L = lane;
    const int b0 = (blockIdx.x * 4 + wid) * 16;
    if (b0 >= B) return;

    char* wb  = smem + wid * WAVE_LDS;
    char* THb = wb;                     // 512
    char* CFb = wb + 512;               // 1088
    char* V4t = wb + 1600;              // 256
    char* RFb = wb + 1856;              // 1024
    char* Rb  = wb + 2880;              // 2176 (VT alias first)
    f4*   VT  = (f4*)Rb;

    // constant frags (loop-invariant), all f16
    const uint2* ft = (const uint2*)((const char*)p + 512);
    half4 Art  = h4(ft[      L]);
    half4 Ait  = h4(ft[ 64 + L]);
    half4 nAit = h4(ft[128 + L]);
    half4 Brf  = h4(ft[192 + L]);
    half4 Bif  = h4(ft[256 + L]);
    half4 nBif = h4(ft[320 + L]);
    const half8* sgt = (const half8*)((const char*)p + 4608);

    // ---- phase A: build V for 16 samples x 8 qubits (2 builds/lane) ----
    {
        int sI = L >> 2, qp = (L & 3) * 2;
        float2 xv  = ((const float2*)x)[(size_t)(b0 + sI)*4 + (L & 3)];
        float2 w0p = ((const float2*)p)[qp >> 1];
        const f4* Kt = (const f4*)(p + 8);
#pragma unroll
        for (int u = 0; u < 2; ++u) {
            int q = qp + u;
            float ang = (u ? xv.y : xv.x) + (u ? w0p.y : w0p.x);
            float rev = ang * 0.07957747154594767f;      // (ang/2)/(2pi)
            float ca = __builtin_amdgcn_cosf(rev);
            float sa = __builtin_amdgcn_sinf(rev);
            f4 Ka = Kt[q*2], Kb = Kt[q*2+1];
            f4 v;
            v.x = ca*Ka.x + sa*Ka.z;  v.y = ca*Ka.y + sa*Ka.w;   // V0
            v.z = ca*Kb.x + sa*Kb.z;  v.w = ca*Kb.y + sa*Kb.w;   // V1
            VT[sI*8 + q] = v;
        }
    }
    // same-wave LDS is in-order; all regions per-wave -> no barriers

    // ---- phase B: build TH/cf/V4/RF tables in f16 (4 lanes per sample) ----
    {
        int sI = L >> 2, j = L & 3;
        const f4* Vs = VT + sI*8;
        f4 q0v = Vs[0], q1v = Vs[1], q2v = Vs[2], q3v = Vs[3];
        f4 q4v = Vs[4], q5v = Vs[5], q6v = Vs[6], q7v = Vs[7];
        f2 V0a = {q0v.x,q0v.y}, V0b = {q0v.z,q0v.w};
        f2 V1a = {q1v.x,q1v.y}, V1b = {q1v.z,q1v.w};
        f2 V2a = {q2v.x,q2v.y}, V2b = {q2v.z,q2v.w};
        f2 V3a = {q3v.x,q3v.y}, V3b = {q3v.z,q3v.w};
        f2 V4a = {q4v.x,q4v.y}, V4bv = {q4v.z,q4v.w};
        f2 V5a = {q5v.x,q5v.y}, V5b = {q5v.z,q5v.w};
        f2 V6a = {q6v.x,q6v.y}, V6b = {q6v.z,q6v.w};
        f2 V7a = {q7v.x,q7v.y}, V7b = {q7v.z,q7v.w};
        // TH slot j = (t1,t2) = (j>>1, j&1); entries col0 = 0,1  (f16)
        int t1 = j >> 1, t2 = j & 1;
        f2 th0 = cmul_pk(t1 ? V0b : V0a, t2 ? V1b : V1a);
        f2 th1 = cmul_pk(t1 ? V0a : V0b, t2 ? V1a : V1b);
        *(uint2*)(THb + sI*32 + j*8) = (uint2){pkh(th0), pkh(th1)};
        // cf for cols 4j..4j+3 (f16): col3 = j>>1, col2 = j&1
        int col3 = j >> 1, col2 = j & 1;
        f2 v5s  = (col3 ^ col2) ? V5b : V5a;
        f2 p6_0 = cmul_pk(v5s, col2 ? V6b : V6a);     // col1 = 0
        f2 p6_1 = cmul_pk(v5s, col2 ? V6a : V6b);     // col1 = 1
#pragma unroll
        for (int c = 0; c < 4; ++c) {
            int c1 = c >> 1, c0 = c & 1;
            f2 cf = cmul_pk(c1 ? p6_1 : p6_0, (c1 ^ c0) ? V7b : V7a);
            *(unsigned*)(CFb + sI*68 + (4*j + c)*4) = pkh(cf);
        }
        // V4 table: entry[col3] = (V4[col3], V4[1^col3])  (j<2 writes)
        if (j < 2) {
            f2 lo = j ? V4bv : V4a, hi = j ? V4a : V4bv;
            *(uint2*)(V4t + sI*16 + j*8) = (uint2){pkh(lo), pkh(hi)};
        }
        // RF rows 4j..4j+3 (f16): RF[row] = V2[row2^row1]*V3[row1^row0]
        unsigned rr[4];
#pragma unroll
        for (int r = 0; r < 4; ++r) {
            int r1 = r >> 1, r0 = r & 1;
            f2 rf = cmul_pk(((j & 1) ^ r1) ? V2b : V2a, (r1 ^ r0) ? V3b : V3a);
            rr[r] = pkh(rf);
        }
        *(uint4*)(RFb + sI*64 + j*16) = (uint4){rr[0], rr[1], rr[2], rr[3]};
    }

    // ---- hoisted lane constants ----
    const int hq  = L >> 4;             // quad
    const int col = L & 15;
    const int th_t1 = hq >> 1, th_t2 = (hq >> 1) ^ (hq & 1);
    char* THl = THb + ((th_t1*2 + th_t2)*2 + (col & 1))*4;
    char* CFl = CFb + col*4;
    char* V4l = V4t + (col >> 3)*8;
    char* RFl = RFb + hq*16;
    char* Rw  = Rb + L*8;
    char* Rr  = Rb + (col & 3)*544 + hq*16;
    const f4 zz = {0.f, 0.f, 0.f, 0.f};

    for (int h = 0; h < 4; ++h) {
        for (int s4 = 0; s4 < 4; ++s4) {
            const int s = h*4 + s4;
            // ---- front-end (all f16): a_r = RF[4hq+r] * TH * cf * V4 ----
            unsigned u  = *(const unsigned*)(THl + s*32);
            unsigned cf = *(const unsigned*)(CFl + s*68);
            uint2   v4  = *(const uint2*)(V4l + s*16);
            uint4   rf  = *(const uint4*)(RFl + s*64);
            unsigned g  = cmulh(u, cf);
            unsigned gl = cmulh(g, v4.x);
            unsigned gh = cmulh(g, v4.y);
            unsigned a0 = cmulh(rf.x, gl);
            unsigned a1 = cmulh(rf.y, gh);
            unsigned a2 = cmulh(rf.z, gl);
            unsigned a3 = cmulh(rf.w, gh);
            // a_j = S[quad*4+j][col] = S^T A-operand rows; split re/im
            half4 Srf = h4((uint2){ __builtin_amdgcn_perm(a1, a0, 0x05040100u),
                                    __builtin_amdgcn_perm(a3, a2, 0x05040100u) });
            half4 Sif = h4((uint2){ __builtin_amdgcn_perm(a1, a0, 0x07060302u),
                                    __builtin_amdgcn_perm(a3, a2, 0x07060302u) });
            // ---- stage-1: T = S^T * A^T  (= M^T), 4x mfma 16x16x16 ----
            f4 Tr4 = mfma16(Sif, nAit, mfma16(Srf, Art, zz));
            f4 Ti4 = mfma16(Sif, Art,  mfma16(Srf, Ait, zz));
            // C layout == B-operand layout: pack rows quad*4+r to f16
            half4 Trf = h4((uint2){ pkh((f2){Tr4[0], Tr4[1]}),
                                    pkh((f2){Tr4[2], Tr4[3]}) });
            half4 Tif = h4((uint2){ pkh((f2){Ti4[0], Ti4[1]}),
                                    pkh((f2){Ti4[2], Ti4[3]}) });
            // ---- stage-2: phi^T = B * T, 4x mfma 16x16x16 ----
            f4 Pr4 = mfma16(nBif, Tif, mfma16(Brf, Trf, zz));
            f4 Pi4 = mfma16(Bif,  Trf, mfma16(Brf, Tif, zz));
            // ---- probs + in-lane 4-WHT (over wires 6,7) -> 3 classes ----
            float Q0 = Pr4[0]*Pr4[0] + Pi4[0]*Pi4[0];
            float Q1 = Pr4[1]*Pr4[1] + Pi4[1]*Pi4[1];
            float Q2 = Pr4[2]*Pr4[2] + Pi4[2]*Pi4[2];
            float Q3 = Pr4[3]*Pr4[3] + Pi4[3]*Pi4[3];
            float s01 = Q0 + Q1, s23 = Q2 + Q3;
            float S00 = s01 + s23;
            float S10 = s01 - s23;              // sign by w6
            float S11 = (Q0 - Q1) - (Q2 - Q3);  // sign by w6^w7
            uint2 wv = { pkh((f2){S00, S10}), pkh((f2){S11, 0.f}) };
            *(uint2*)(Rw + s4*544) = wv;
        }
        // ---- epilogue: out[s][w] = R x Sgn (8 chained f16 MFMAs) ----
        f4 acc = zz;
#pragma unroll
        for (int tt = 0; tt < 8; ++tt) {
            uint4 rv = *(uint4*)(Rr + tt*64);
            half8 af;
            __builtin_memcpy(&af, &rv, 16);
            acc = __builtin_amdgcn_mfma_f32_16x16x32_f16(af, sgt[tt*64 + L], acc, 0, 0, 0);
        }
        if (hq == 0 && col < 8) {       // rows 0..3 = samples h*4..h*4+3
            size_t base = (size_t)(b0 + h*4) * 8 + col;
            out[base     ] = acc[0];
            out[base +  8] = acc[1];
            out[base + 16] = acc[2];
            out[base + 24] = acc[3];
        }
    }
}

extern "C" void kernel_launch(void* const* d_in, const int* in_sizes, int n_in,
                              void* d_out, int out_size, void* d_ws, size_t ws_size,
                              hipStream_t stream) {
    const float* x = (const float*)d_in[0];
    const float* w = (const float*)d_in[1];
    float* outp    = (float*)d_out;
    float* params  = (float*)d_ws;        // ~12.8 KB used
    int B = in_sizes[0] / 8;

    qnn_setup<<<1, 256, 0, stream>>>(w, params);
    int blocks = (B + 63) / 64;           // 4 waves/block, 16 samples/wave
    qnn_main<<<blocks, 256, 0, stream>>>(x, params, outp, B);
}

// Round 13
// 83.745 us; speedup vs baseline: 1.2043x; 1.0017x over previous
//
#include <hip/hip_runtime.h>
#include <math.h>

// QNN: 8 qubits, DIM=256, 2 entangling layers, B samples.
//  - RX(x_q) fuses with layer-1 RX -> product state v_q (V0,V1).
//  - CNOT ring 1 folded into product expansion; rank-8 split (R7/R9):
//      S[row][col] = RF[row] * TH[(h1,h1^h0)][col0] * TC[col][r0]
//  - Layer-2: phi = A*S*B^T computed as T = S^T*A^T then phi^T = B*T with
//    mfma_f32_16x16x16f16 (R12): A/B operand layout == C/D layout, so the
//    front-end feeds stage-1 directly and stage-1 feeds stage-2 directly —
//    zero LDS round-trips in the matmul.
//  - CNOT ring 2 + <Z_w> + reduction folded into a constant sign matrix
//    applied as mfma 16x16x32 f16 chain (R6), phi^T bit mapping (R12).
// R13: front-end reverted to R9's full-TC tables (3 LDS reads + 6 cmulh vs
//      R10's 4 reads + 7 cmulh split, which existed only to fund S-staging
//      LDS that R12 deleted). 5888 B/wave -> 24576/block -> 6 blocks/CU.

typedef float f2 __attribute__((ext_vector_type(2)));
typedef float f4 __attribute__((ext_vector_type(4)));
typedef _Float16 half4 __attribute__((ext_vector_type(4)));
typedef _Float16 half8 __attribute__((ext_vector_type(8)));

// f32 complex mul, 2 VOP3P ops (verified R3-R12) - table-build phase
__device__ __forceinline__ f2 cmul_pk(f2 a, f2 b) {
    f2 t, d;
    asm("v_pk_mul_f32 %0, %1, %2 op_sel:[0,0] op_sel_hi:[0,1]"
        : "=v"(t) : "v"(a), "v"(b));
    asm("v_pk_fma_f32 %0, %1, %2, %3 op_sel:[1,1,0] op_sel_hi:[1,0,1] neg_lo:[1,0,0] neg_hi:[0,0,0]"
        : "=v"(d) : "v"(a), "v"(b), "v"(t));
    return d;
}
// packed-f16 complex mul (verified R9-R12)
__device__ __forceinline__ unsigned cmulh(unsigned a, unsigned b) {
    unsigned t, d;
    asm("v_pk_mul_f16 %0, %1, %2 op_sel:[0,0] op_sel_hi:[0,1]"
        : "=v"(t) : "v"(a), "v"(b));
    asm("v_pk_fma_f16 %0, %1, %2, %3 op_sel:[1,1,0] op_sel_hi:[1,0,1] neg_lo:[1,0,0] neg_hi:[0,0,0]"
        : "=v"(d) : "v"(a), "v"(b), "v"(t));
    return d;
}
__device__ __forceinline__ unsigned pkh(f2 v) {
    auto pk = __builtin_amdgcn_cvt_pkrtz(v.x, v.y);
    unsigned u; __builtin_memcpy(&u, &pk, 4);
    return u;
}
__device__ __forceinline__ half4 h4(uint2 u) {
    half4 h; __builtin_memcpy(&h, &u, 8);
    return h;
}
__device__ __forceinline__ f4 mfma16(half4 a, half4 b, f4 c) {
    return __builtin_amdgcn_mfma_f32_16x16x16f16(a, b, c, 0, 0, 0);
}

// ---------------- setup (identical to R12) ----------------
// d_ws bytes: 0..511 floats (w0 + K-tables);
//   512: S1Ar | 1024: S1Ai | 1536: S1nAi   (A^T in 16x16x16 B-layout, f16)
//   2048: S2Br | 2560: S2Bi | 3072: S2nBi  (B   in 16x16x16 A-layout, f16)
//   4608..12799: sign table SG (f16, 16x16x32 A-layout chunks)
__global__ void qnn_setup(const float* __restrict__ w, float* __restrict__ p) {
    int t = threadIdx.x;
    if (t < 8) {
        int q = t;
        float cb = cosf(w[q*3+1]*0.5f), sb = sinf(w[q*3+1]*0.5f);
        float cg = cosf(w[q*3+2]*0.5f), sg = sinf(w[q*3+2]*0.5f);
        p[q] = w[q*3+0];
        float* K = p + 8 + q*8;
        K[0] = cg*cb;  K[1] = -sg*cb;      // K1
        K[2] = sg*sb;  K[3] = cg*sb;       // K2
        K[4] = cg*sb;  K[5] = sg*sb;       // K3
        K[6] = sg*cb;  K[7] = -cg*cb;      // K4
    }
    float G[8][2][2][2];
    for (int q = 0; q < 8; ++q) {
        const float* wq = w + (8+q)*3;
        float ca = cosf(wq[0]*0.5f), sa = sinf(wq[0]*0.5f);
        float cb = cosf(wq[1]*0.5f), sb = sinf(wq[1]*0.5f);
        float cg = cosf(wq[2]*0.5f), sg = sinf(wq[2]*0.5f);
        float A = cb*ca, Bv = sb*sa, C = sb*ca, D = cb*sa;
        float g00r = cg*A + sg*Bv, g00i = cg*Bv - sg*A;
        float g01r = -(cg*C + sg*D), g01i = sg*C - cg*D;
        G[q][0][0][0]=g00r;  G[q][0][0][1]=g00i;
        G[q][0][1][0]=g01r;  G[q][0][1][1]=g01i;
        G[q][1][0][0]=-g01r; G[q][1][0][1]=g01i;
        G[q][1][1][0]=g00r;  G[q][1][1][1]=-g00i;
    }
    int m = t & 15, k2 = t >> 4;
    float ar = 1.f, ai = 0.f, br = 1.f, bi = 0.f;
    for (int j = 0; j < 4; ++j) {
        int bm = (m >> (3-j)) & 1, bk = (k2 >> (3-j)) & 1;
        float gr = G[j][bm][bk][0],  gi = G[j][bm][bk][1];
        float nr = ar*gr - ai*gi, ni = ar*gi + ai*gr; ar = nr; ai = ni;
        float hr = G[4+j][bm][bk][0], hi = G[4+j][bm][bk][1];
        float mr = br*hr - bi*hi, mi = br*hi + bi*hr; br = mr; bi = mi;
    }
    _Float16* S1Ar  = (_Float16*)((char*)p +  512);
    _Float16* S1Ai  = (_Float16*)((char*)p + 1024);
    _Float16* S1nAi = (_Float16*)((char*)p + 1536);
    _Float16* S2Br  = (_Float16*)((char*)p + 2048);
    _Float16* S2Bi  = (_Float16*)((char*)p + 2560);
    _Float16* S2nBi = (_Float16*)((char*)p + 3072);
    int idx = ((k2 >> 2)*16 + m)*4 + (k2 & 3);
    S1Ar[idx]  = (_Float16)ar;
    S1Ai[idx]  = (_Float16)ai;
    S1nAi[idx] = (_Float16)(-ai);
    S2Br[idx]  = (_Float16)br;
    S2Bi[idx]  = (_Float16)bi;
    S2nBi[idx] = (_Float16)(-bi);

    // sign table - phi^T bit assignment (R12, verified):
    const int cls[8] = {2, 0, 0, 0, 0, 0, 1, 2};
    const int msk[8] = {55, 12, 14, 15, 47, 63, 63, 63};
    _Float16* SG = (_Float16*)((char*)p + 4608);
    for (int e = t; e < 512; e += 256) {
        int tt = e >> 6, l = e & 63, n = l & 15, quad = l >> 4;
        for (int j = 0; j < 8; ++j) {
            int k  = tt*32 + quad*8 + j;
            int Lp = k >> 2, c = k & 3;
            float v = 0.f;
            if (n < 8 && c == cls[n])
                v = (__popc(msk[n] & Lp) & 1) ? -1.f : 1.f;
            SG[e*8 + j] = (_Float16)v;
        }
    }
}

// per-wave LDS (5888 B -> 6144; block 24576 -> 6 blocks/CU):
//   TH 512 | TC 2176 (stride 136) | RF 1024 (stride 64) |
//   R 2176 (4 rows x 544)  [VT 2048 aliased into R, dead before R writes]
#define WAVE_LDS 6144

__global__ __launch_bounds__(256, 6) void qnn_main(
        const float* __restrict__ x, const float* __restrict__ p,
        float* __restrict__ out, int B)
{
    __shared__ __align__(16) char smem[4 * WAVE_LDS];
    const int lane = threadIdx.x & 63;
    const int wid  = threadIdx.x >> 6;
    const int L = lane;
    const int b0 = (blockIdx.x * 4 + wid) * 16;
    if (b0 >= B) return;

    char* wb  = smem + wid * WAVE_LDS;
    char* THb = wb;                     // 512
    char* TCb = wb + 512;               // 2176
    char* RFb = wb + 2688;              // 1024
    char* Rb  = wb + 3712;              // 2176 (VT alias first)
    f4*   VT  = (f4*)Rb;

    // constant frags (loop-invariant), all f16
    const uint2* ft = (const uint2*)((const char*)p + 512);
    half4 Art  = h4(ft[      L]);
    half4 Ait  = h4(ft[ 64 + L]);
    half4 nAit = h4(ft[128 + L]);
    half4 Brf  = h4(ft[192 + L]);
    half4 Bif  = h4(ft[256 + L]);
    half4 nBif = h4(ft[320 + L]);
    const half8* sgt = (const half8*)((const char*)p + 4608);

    // ---- phase A: build V for 16 samples x 8 qubits (2 builds/lane) ----
    {
        int sI = L >> 2, qp = (L & 3) * 2;
        float2 xv  = ((const float2*)x)[(size_t)(b0 + sI)*4 + (L & 3)];
        float2 w0p = ((const float2*)p)[qp >> 1];
        const f4* Kt = (const f4*)(p + 8);
#pragma unroll
        for (int u = 0; u < 2; ++u) {
            int q = qp + u;
            float ang = (u ? xv.y : xv.x) + (u ? w0p.y : w0p.x);
            float rev = ang * 0.07957747154594767f;      // (ang/2)/(2pi)
            float ca = __builtin_amdgcn_cosf(rev);
            float sa = __builtin_amdgcn_sinf(rev);
            f4 Ka = Kt[q*2], Kb = Kt[q*2+1];
            f4 v;
            v.x = ca*Ka.x + sa*Ka.z;  v.y = ca*Ka.y + sa*Ka.w;   // V0
            v.z = ca*Kb.x + sa*Kb.z;  v.w = ca*Kb.y + sa*Kb.w;   // V1
            VT[sI*8 + q] = v;
        }
    }
    // same-wave LDS is in-order; all regions per-wave -> no barriers

    // ---- phase B: build TH/TC/RF tables in f16 (4 lanes per sample) ----
    {
        int sI = L >> 2, j = L & 3;
        const f4* Vs = VT + sI*8;
        f4 q0v = Vs[0], q1v = Vs[1], q2v = Vs[2], q3v = Vs[3];
        f4 q4v = Vs[4], q5v = Vs[5], q6v = Vs[6], q7v = Vs[7];
        f2 V0a = {q0v.x,q0v.y}, V0b = {q0v.z,q0v.w};
        f2 V1a = {q1v.x,q1v.y}, V1b = {q1v.z,q1v.w};
        f2 V2a = {q2v.x,q2v.y}, V2b = {q2v.z,q2v.w};
        f2 V3a = {q3v.x,q3v.y}, V3b = {q3v.z,q3v.w};
        f2 V4a = {q4v.x,q4v.y}, V4bv = {q4v.z,q4v.w};
        f2 V5a = {q5v.x,q5v.y}, V5b = {q5v.z,q5v.w};
        f2 V6a = {q6v.x,q6v.y}, V6b = {q6v.z,q6v.w};
        f2 V7a = {q7v.x,q7v.y}, V7b = {q7v.z,q7v.w};
        // TH slot j = (t1,t2) = (j>>1, j&1); entries col0 = 0,1  (f16)
        int t1 = j >> 1, t2 = j & 1;
        f2 th0 = cmul_pk(t1 ? V0b : V0a, t2 ? V1b : V1a);
        f2 th1 = cmul_pk(t1 ? V0a : V0b, t2 ? V1a : V1b);
        *(uint2*)(THb + sI*32 + j*8) = (uint2){pkh(th0), pkh(th1)};
        // TC cols 4j..4j+3 (f16): col3 = j>>1, col2 = j&1 (R9 layout)
        int col3 = j >> 1, col2 = j & 1;
        f2 v5s  = (col3 ^ col2) ? V5b : V5a;
        f2 p6_0 = cmul_pk(v5s, col2 ? V6b : V6a);     // col1 = 0
        f2 p6_1 = cmul_pk(v5s, col2 ? V6a : V6b);     // col1 = 1
        f2 V4lo = col3 ? V4bv : V4a;                  // V4[col3]     (r0=0)
        f2 V4hi = col3 ? V4a : V4bv;                  // V4[1^col3]   (r0=1)
#pragma unroll
        for (int c = 0; c < 4; ++c) {
            int c1 = c >> 1, c0 = c & 1;
            f2 cf = cmul_pk(c1 ? p6_1 : p6_0, (c1 ^ c0) ? V7b : V7a);
            f2 e0 = cmul_pk(cf, V4lo);
            f2 e1 = cmul_pk(cf, V4hi);
            *(uint2*)(TCb + sI*136 + (4*j + c)*8) = (uint2){pkh(e0), pkh(e1)};
        }
        // RF rows 4j..4j+3 (f16): RF[row] = V2[row2^row1]*V3[row1^row0]
        unsigned rr[4];
#pragma unroll
        for (int r = 0; r < 4; ++r) {
            int r1 = r >> 1, r0 = r & 1;
            f2 rf = cmul_pk(((j & 1) ^ r1) ? V2b : V2a, (r1 ^ r0) ? V3b : V3a);
            rr[r] = pkh(rf);
        }
        *(uint4*)(RFb + sI*64 + j*16) = (uint4){rr[0], rr[1], rr[2], rr[3]};
    }

    // ---- hoisted lane constants ----
    const int hq  = L >> 4;             // quad
    const int col = L & 15;
    const int th_t1 = hq >> 1, th_t2 = (hq >> 1) ^ (hq & 1);
    char* THl = THb + ((th_t1*2 + th_t2)*2 + (col & 1))*4;
    char* TCl = TCb + col*8;
    char* RFl = RFb + hq*16;
    char* Rw  = Rb + L*8;
    char* Rr  = Rb + (col & 3)*544 + hq*16;
    const f4 zz = {0.f, 0.f, 0.f, 0.f};

    for (int h = 0; h < 4; ++h) {
#pragma unroll
        for (int s4 = 0; s4 < 4; ++s4) {
            const int s = h*4 + s4;
            // ---- front-end (R9 form): a_r = RF[4hq+r] * (TH*TC[col][r&1]) --
            unsigned u  = *(const unsigned*)(THl + s*32);
            uint2   tc  = *(const uint2*)(TCl + s*136);
            uint4   rf  = *(const uint4*)(RFl + s*64);
            unsigned g0 = cmulh(u, tc.x);
            unsigned g1 = cmulh(u, tc.y);
            unsigned a0 = cmulh(rf.x, g0);
            unsigned a1 = cmulh(rf.y, g1);
            unsigned a2 = cmulh(rf.z, g0);
            unsigned a3 = cmulh(rf.w, g1);
            // a_j = S[quad*4+j][col] = S^T A-operand rows; split re/im
            half4 Srf = h4((uint2){ __builtin_amdgcn_perm(a1, a0, 0x05040100u),
                                    __builtin_amdgcn_perm(a3, a2, 0x05040100u) });
            half4 Sif = h4((uint2){ __builtin_amdgcn_perm(a1, a0, 0x07060302u),
                                    __builtin_amdgcn_perm(a3, a2, 0x07060302u) });
            // ---- stage-1: T = S^T * A^T  (= M^T), 4x mfma 16x16x16 ----
            f4 Tr4 = mfma16(Sif, nAit, mfma16(Srf, Art, zz));
            f4 Ti4 = mfma16(Sif, Art,  mfma16(Srf, Ait, zz));
            // C layout == B-operand layout: pack rows quad*4+r to f16
            half4 Trf = h4((uint2){ pkh((f2){Tr4[0], Tr4[1]}),
                                    pkh((f2){Tr4[2], Tr4[3]}) });
            half4 Tif = h4((uint2){ pkh((f2){Ti4[0], Ti4[1]}),
                                    pkh((f2){Ti4[2], Ti4[3]}) });
            // ---- stage-2: phi^T = B * T, 4x mfma 16x16x16 ----
            f4 Pr4 = mfma16(nBif, Tif, mfma16(Brf, Trf, zz));
            f4 Pi4 = mfma16(Bif,  Trf, mfma16(Brf, Tif, zz));
            // ---- probs + in-lane 4-WHT (over wires 6,7) -> 3 classes ----
            float Q0 = Pr4[0]*Pr4[0] + Pi4[0]*Pi4[0];
            float Q1 = Pr4[1]*Pr4[1] + Pi4[1]*Pi4[1];
            float Q2 = Pr4[2]*Pr4[2] + Pi4[2]*Pi4[2];
            float Q3 = Pr4[3]*Pr4[3] + Pi4[3]*Pi4[3];
            float s01 = Q0 + Q1, s23 = Q2 + Q3;
            float S00 = s01 + s23;
            float S10 = s01 - s23;              // sign by w6
            float S11 = (Q0 - Q1) - (Q2 - Q3);  // sign by w6^w7
            uint2 wv = { pkh((f2){S00, S10}), pkh((f2){S11, 0.f}) };
            *(uint2*)(Rw + s4*544) = wv;
        }
        // ---- epilogue: out[s][w] = R x Sgn (8 chained f16 MFMAs) ----
        f4 acc = zz;
#pragma unroll
        for (int tt = 0; tt < 8; ++tt) {
            uint4 rv = *(uint4*)(Rr + tt*64);
            half8 af;
            __builtin_memcpy(&af, &rv, 16);
            acc = __builtin_amdgcn_mfma_f32_16x16x32_f16(af, sgt[tt*64 + L], acc, 0, 0, 0);
        }
        if (hq == 0 && col < 8) {       // rows 0..3 = samples h*4..h*4+3
            size_t base = (size_t)(b0 + h*4) * 8 + col;
            out[base     ] = acc[0];
            out[base +  8] = acc[1];
            out[base + 16] = acc[2];
            out[base + 24] = acc[3];
        }
    }
}

extern "C" void kernel_launch(void* const* d_in, const int* in_sizes, int n_in,
                              void* d_out, int out_size, void* d_ws, size_t ws_size,
                              hipStream_t stream) {
    const float* x = (const float*)d_in[0];
    const float* w = (const float*)d_in[1];
    float* outp    = (float*)d_out;
    float* params  = (float*)d_ws;        // ~12.8 KB used
    int B = in_sizes[0] / 8;

    qnn_setup<<<1, 256, 0, stream>>>(w, params);
    int blocks = (B + 63) / 64;           // 4 waves/block, 16 samples/wave
    qnn_main<<<blocks, 256, 0, stream>>>(x, params, outp, B);
}